// Round 11
// baseline (316.354 us; speedup 1.0000x reference)
//
#include <hip/hip_runtime.h>
#include <hip/hip_bf16.h>

// Problem constants
constexpr int kB   = 2;
constexpr int kS   = 2048;
constexpr int kD   = 1024;
constexpr int kH   = 16;
constexpr int kDh  = 64;
constexpr int kBS  = kB * kS;          // 4096 rows

typedef __attribute__((ext_vector_type(8))) short short8;   // 8 bf16 = 4 VGPRs
typedef __attribute__((ext_vector_type(4))) float floatx4;  // MFMA acc

__device__ inline unsigned short f2b(float f) {
    __hip_bfloat16 h = __float2bfloat16(f);
    return *reinterpret_cast<unsigned short*>(&h);
}

__device__ inline float b2f(unsigned short u) {
    union { unsigned u; float f; } cv;
    cv.u = (unsigned)u << 16;
    return cv.f;
}

__device__ inline floatx4 mfma16(short8 a, short8 b, floatx4 c) {
    return __builtin_amdgcn_mfma_f32_16x16x32_bf16(a, b, c, 0, 0, 0);
}

// async global->LDS, 16B per lane; LDS dest = wave-uniform base + lane*16
__device__ inline void gload16(const unsigned short* g, unsigned short* l) {
    __builtin_amdgcn_global_load_lds(
        (const __attribute__((address_space(1))) void*)g,
        (__attribute__((address_space(3))) void*)l, 16, 0, 0);
}

// ---------------------------------------------------------------------------
// K0: fp32 -> bf16 conversion of x (4M elems) and the 4 weights (4 x 1M elems)
// ---------------------------------------------------------------------------
__global__ void convert_kernel(const float* __restrict__ x,
                               const float* __restrict__ wq, const float* __restrict__ wk,
                               const float* __restrict__ wv, const float* __restrict__ wo,
                               unsigned short* __restrict__ xb, unsigned short* __restrict__ wb) {
    int gid = blockIdx.x * blockDim.x + threadIdx.x;
    long i4 = (long)gid * 4;
    const float* src;
    unsigned short* dst;
    long off;
    if (i4 < (long)kBS * kD) {
        src = x; dst = xb; off = i4;
    } else {
        long w = i4 - (long)kBS * kD;
        int sel = (int)(w >> 20);
        off = w & 1048575;
        src = (sel == 0) ? wq : (sel == 1) ? wk : (sel == 2) ? wv : wo;
        dst = wb + (long)sel * 1048576;
    }
    float4 v = *(const float4*)(src + off);
    ushort4 o;
    o.x = f2b(v.x); o.y = f2b(v.y); o.z = f2b(v.z); o.w = f2b(v.w);
    *(ushort4*)(dst + off) = o;
}

// ---------------------------------------------------------------------------
// K1: NT GEMM  C[M,N] = A[M,K] @ B[N,K]^T   (bf16 in, fp32 accum)
// m97-style staging: global_load_lds width=16, XOR-swizzled k-chunks.
// MODE 0: bf16 C; z==0 (Q) scaled by 0.125*log2(e) (exp2 domain).
// MODE 1: fp32 C + residual.
// ---------------------------------------------------------------------------
template <int MODE>
__launch_bounds__(256, 2)
__global__ void gemm_nt(const unsigned short* __restrict__ A,
                        const unsigned short* __restrict__ Bw,
                        void* __restrict__ Cout,
                        const float* __restrict__ resid,
                        int M, int N, int K) {
    __shared__ __align__(16) unsigned short As[128 * 32];
    __shared__ __align__(16) unsigned short Bs[128 * 32];

    const int z  = blockIdx.z;
    const unsigned short* Bp = Bw + (size_t)z * N * K;
    const int m0 = blockIdx.y * 128, n0 = blockIdx.x * 128;
    const int tid  = threadIdx.x;
    const int lane = tid & 63, wv = tid >> 6;
    const int wm = wv >> 1, wn = wv & 1;
    const int quad = lane >> 4, l16 = lane & 15;

    floatx4 acc[4][4] = {};

    const int c0 = wv * 64 + lane;          // 0..255   (rows 0..63)
    const int c1 = 256 + c0;                // 256..511 (rows 64..127)
    const int ar0 = c0 >> 2, aj0 = ((c0 & 3) ^ (ar0 & 3)) * 8;
    const int ar1 = c1 >> 2, aj1 = ((c1 & 3) ^ (ar1 & 3)) * 8;
    const unsigned short* Ag0 = A  + (size_t)(m0 + ar0) * K + aj0;
    const unsigned short* Ag1 = A  + (size_t)(m0 + ar1) * K + aj1;
    const unsigned short* Bg0 = Bp + (size_t)(n0 + ar0) * K + aj0;
    const unsigned short* Bg1 = Bp + (size_t)(n0 + ar1) * K + aj1;
    unsigned short* Asd0 = As + wv * 512;
    unsigned short* Asd1 = As + (4 + wv) * 512;
    unsigned short* Bsd0 = Bs + wv * 512;
    unsigned short* Bsd1 = Bs + (4 + wv) * 512;

    for (int k0 = 0; k0 < K; k0 += 32) {
        __syncthreads();
        gload16(Ag0 + k0, Asd0);
        gload16(Ag1 + k0, Asd1);
        gload16(Bg0 + k0, Bsd0);
        gload16(Bg1 + k0, Bsd1);
        __syncthreads();

        short8 af[4], bf[4];
#pragma unroll
        for (int i = 0; i < 4; i++) {
            const int R = wm * 64 + i * 16 + l16;
            af[i] = *(const short8*)(As + R * 32 + (quad ^ (l16 & 3)) * 8);
        }
#pragma unroll
        for (int j = 0; j < 4; j++) {
            const int R = wn * 64 + j * 16 + l16;
            bf[j] = *(const short8*)(Bs + R * 32 + (quad ^ (l16 & 3)) * 8);
        }
#pragma unroll
        for (int i = 0; i < 4; i++)
#pragma unroll
            for (int j = 0; j < 4; j++)
                acc[i][j] = mfma16(af[i], bf[j], acc[i][j]);
    }

#pragma unroll
    for (int i = 0; i < 4; i++)
#pragma unroll
        for (int j = 0; j < 4; j++) {
            const int row = m0 + wm * 64 + i * 16 + quad * 4;
            const int col = n0 + wn * 64 + j * 16 + l16;
#pragma unroll
            for (int r = 0; r < 4; r++) {
                float v = acc[i][j][r];
                if (MODE == 0) {
                    if (z == 0) v *= 0.18033688f;   // 0.125 * log2(e)
                    ((unsigned short*)Cout)[(size_t)z * M * N + (size_t)(row + r) * N + col] = f2b(v);
                } else {
                    size_t idx = (size_t)(row + r) * N + col;
                    ((float*)Cout)[idx] = v + resid[idx];
                }
            }
        }
}

// ---------------------------------------------------------------------------
// K2: FUSED column-softmax denominators + scaled V^T — SINGLE-WAVE blocks.
// Block = 64 threads = 1 wave owning 32 keys; grid 2048 (64 keyblk x 32 bh,
// XCD-swizzled). __syncthreads in a 1-wave block is just the wave's own
// waitcnt — no cross-wave barrier coupling; waves self-pace.
// Phase 1: invl[k] = 1/sum_q exp2(s[q,k]); Q-tile (64x64) staged per chunk.
// Phase 2: VT[bh][d][keyblk*32..+32] = V * invl via LDS transpose.
// ---------------------------------------------------------------------------
__launch_bounds__(64, 2)
__global__ void stats_vt_kernel(const unsigned short* __restrict__ Qb,
                                const unsigned short* __restrict__ Kb,
                                const unsigned short* __restrict__ Vb,
                                unsigned short* __restrict__ VT) {
    __shared__ __align__(16) unsigned short Qs[64 * 64];  // staging / transpose tile (32x65)
    __shared__ float s_inv[32];

    const int id = blockIdx.x;                       // 0..2047
    const int bh = (id & 7) + 8 * ((id >> 3) & 3);   // XCD-grouped
    const int keyblk = id >> 5;                      // 0..63
    const int b = bh >> 4, h = bh & 15;
    const int lane = threadIdx.x;                    // 0..63
    const int quad = lane >> 4, l16 = lane & 15;
    const int keybase = keyblk * 32;

    // A-frags: K rows (2 key-tiles x 2 dh-halves), held in regs
    short8 ak[2][2];
#pragma unroll
    for (int s = 0; s < 2; s++) {
        const unsigned short* Krow = Kb + (size_t)(b * kS + keybase + s * 16 + l16) * kD + h * kDh;
        ak[s][0] = *(const short8*)(Krow + quad * 8);
        ak[s][1] = *(const short8*)(Krow + 32 + quad * 8);
    }

    // staging: 8 segs of 8 rows; lane covers row seg*8 + (lane>>3),
    // logical 16B chunk (lane&7) ^ (row&7)
    const int r0 = lane >> 3;
    const int jc = ((lane & 7) ^ r0) * 8;
    const unsigned short* Qg = Qb + (size_t)(b * kS + r0) * kD + h * kDh + jc;

    const int pk0 = (quad ^ (l16 & 7)) * 8;
    const int pk1 = ((4 + quad) ^ (l16 & 7)) * 8;

    float lacc[2][4] = {};

    for (int q0 = 0; q0 < kS; q0 += 64) {
        __syncthreads();   // 1-wave: own-wave drain only
#pragma unroll
        for (int seg = 0; seg < 8; seg++)
            gload16(Qg + (size_t)(q0 + seg * 8) * kD, Qs + seg * 512);
        __syncthreads();

#pragma unroll
        for (int c = 0; c < 4; c++) {
            const unsigned short* row = Qs + (c * 16 + l16) * 64;
            short8 bq0 = *(const short8*)(row + pk0);
            short8 bq1 = *(const short8*)(row + pk1);
#pragma unroll
            for (int s = 0; s < 2; s++) {
                floatx4 t = {0.f, 0.f, 0.f, 0.f};
                t = mfma16(ak[s][0], bq0, t);
                t = mfma16(ak[s][1], bq1, t);
#pragma unroll
                for (int r = 0; r < 4; r++)
                    lacc[s][r] += exp2f(t[r]);
            }
        }
    }

    // reduce across the 16 l16 lanes within each quad
#pragma unroll
    for (int off = 1; off <= 8; off <<= 1)
#pragma unroll
        for (int s = 0; s < 2; s++)
#pragma unroll
            for (int r = 0; r < 4; r++)
                lacc[s][r] += __shfl_xor(lacc[s][r], off, 64);

    __syncthreads();
    if (l16 == 0) {
#pragma unroll
        for (int s = 0; s < 2; s++)
#pragma unroll
            for (int r = 0; r < 4; r++)
                s_inv[s * 16 + quad * 4 + r] = 1.0f / lacc[s][r];
    }
    __syncthreads();

    // Phase 2: scaled V^T for this block's 32 keys (tile 32x65 in Qs).
    unsigned short* tile = Qs;
    {
        const int kr = lane >> 1, dc = (lane & 1) * 32;
        const float iv = s_inv[kr];
        const unsigned short* src = Vb + (size_t)(b * kS + keybase + kr) * kD + h * kDh + dc;
        unsigned short vs[32];
        *(uint4*)(vs)      = *(const uint4*)(src);
        *(uint4*)(vs + 8)  = *(const uint4*)(src + 8);
        *(uint4*)(vs + 16) = *(const uint4*)(src + 16);
        *(uint4*)(vs + 24) = *(const uint4*)(src + 24);
#pragma unroll
        for (int i = 0; i < 32; i++)
            tile[kr * 65 + dc + i] = f2b(b2f(vs[i]) * iv);
    }
    __syncthreads();
    {
        const int d = lane;                 // 0..63
        unsigned short os[32];
#pragma unroll
        for (int j = 0; j < 32; j++) os[j] = tile[j * 65 + d];
        unsigned short* dst = VT + (size_t)bh * kDh * kS + (size_t)d * kS + keybase;
        *(uint4*)(dst)      = *(uint4*)(os);
        *(uint4*)(dst + 8)  = *(uint4*)(os + 8);
        *(uint4*)(dst + 16) = *(uint4*)(os + 16);
        *(uint4*)(dst + 24) = *(uint4*)(os + 24);
    }
}

// ---------------------------------------------------------------------------
// K3: ctx = exp2(S) @ VT^T — SINGLE-WAVE blocks (round-7 inner code).
// Block = 64 threads = 1 wave owning 32 q; grid 2048 (64 qblk x 32 bh, XCD-
// swizzled). Wave stages its own K-tile + VT-tile (64x64 each) per 64-key
// chunk via global_load_lds w=16 (XOR chunk swizzle); __syncthreads is the
// wave's own drain — 7 independent self-paced waves per CU (LDS 21 KB).
// Per chunk: 16 S-MFMA -> exp2 -> P (stride-72 swizzle, truncating bf16,
// immediate-offset ds ops) -> 16 PV-MFMA.
// ---------------------------------------------------------------------------
__launch_bounds__(64, 2)
__global__ void ctx_kernel(const unsigned short* __restrict__ Qb,
                           const unsigned short* __restrict__ Kb,
                           const unsigned short* __restrict__ VT,
                           unsigned short* __restrict__ Ctx) {
    constexpr int LDP = 72;
    __shared__ __align__(16) unsigned short Ks[64 * 64];
    __shared__ __align__(16) unsigned short VTs[64 * 64];
    __shared__ __align__(16) unsigned short Pt[32 * LDP];

    const int id = blockIdx.x;                       // 0..2047
    const int bh = (id & 7) + 8 * ((id >> 3) & 3);   // XCD-grouped
    const int qblk = id >> 5;                        // 0..63
    const int b = bh >> 4, h = bh & 15;
    const int lane = threadIdx.x;                    // 0..63
    const int quad = lane >> 4, l16 = lane & 15;
    const int qbase = qblk * 32;

    short8 aq[2][2];
#pragma unroll
    for (int s = 0; s < 2; s++) {
        const unsigned short* Qrow = Qb + (size_t)(b * kS + qbase + s * 16 + l16) * kD + h * kDh;
        aq[s][0] = *(const short8*)(Qrow + quad * 8);
        aq[s][1] = *(const short8*)(Qrow + 32 + quad * 8);
    }
    floatx4 acc[2][4] = {};

    const unsigned short* Kbase = Kb + (size_t)(b * kS) * kD + h * kDh;
    const unsigned short* VTb   = VT + (size_t)bh * kDh * kS;

    // staging: 8 segs of 8 rows per tile
    const int r0 = lane >> 3;
    const int jc = ((lane & 7) ^ r0) * 8;
    const unsigned short* Kg = Kbase + (size_t)r0 * kD + jc;   // + (k0 + seg*8)*kD
    const unsigned short* Vg = VTb + (size_t)r0 * kS + jc;     // + seg*8*kS + k0

    unsigned short* P = Pt;
    unsigned short* pw[4];
#pragma unroll
    for (int c = 0; c < 4; c++)
        pw[c] = P + quad * 4 * LDP + (c ^ quad) * 16 + l16;
    const int sw_r = (l16 >> 2) * 16;
    const unsigned short* pr0 = P + l16 * LDP + ((quad * 8) ^ sw_r);
    const unsigned short* pr1 = P + l16 * LDP + ((32 + quad * 8) ^ sw_r);

    const int pk0 = (quad ^ (l16 & 7)) * 8;
    const int pk1 = ((4 + quad) ^ (l16 & 7)) * 8;

    for (int k0 = 0; k0 < kS; k0 += 64) {
        __syncthreads();   // 1-wave: own-wave drain only
#pragma unroll
        for (int seg = 0; seg < 8; seg++) {
            gload16(Kg + (size_t)(k0 + seg * 8) * kD, Ks + seg * 512);
            gload16(Vg + (size_t)(seg * 8) * kS + k0, VTs + seg * 512);
        }
        __syncthreads();

        short8 bk[4][2];
#pragma unroll
        for (int c = 0; c < 4; c++) {
            const unsigned short* row = Ks + (c * 16 + l16) * 64;
            bk[c][0] = *(const short8*)(row + pk0);
            bk[c][1] = *(const short8*)(row + pk1);
        }
        floatx4 sc[2][4];
#pragma unroll
        for (int s = 0; s < 2; s++)
#pragma unroll
            for (int c = 0; c < 4; c++) {
                floatx4 t = {0.f, 0.f, 0.f, 0.f};
                t = mfma16(aq[s][0], bk[c][0], t);
                sc[s][c] = mfma16(aq[s][1], bk[c][1], t);
            }
        // exp2 -> P: truncating bf16 store, immediate-offset ds ops
#pragma unroll
        for (int s = 0; s < 2; s++)
#pragma unroll
            for (int c = 0; c < 4; c++)
#pragma unroll
                for (int r = 0; r < 4; r++) {
                    union { float f; unsigned u; } cv;
                    cv.f = exp2f(sc[s][c][r]);
                    pw[c][(s * 16 + r) * LDP] = (unsigned short)(cv.u >> 16);
                }

        short8 bv[4][2];
#pragma unroll
        for (int t = 0; t < 4; t++) {
            const unsigned short* row = VTs + (t * 16 + l16) * 64;
            bv[t][0] = *(const short8*)(row + pk0);
            bv[t][1] = *(const short8*)(row + pk1);
        }
#pragma unroll
        for (int s = 0; s < 2; s++) {
            short8 ap0 = *(const short8*)(pr0 + s * 16 * LDP);
            short8 ap1 = *(const short8*)(pr1 + s * 16 * LDP);
#pragma unroll
            for (int t = 0; t < 4; t++) {
                acc[s][t] = mfma16(ap0, bv[t][0], acc[s][t]);
                acc[s][t] = mfma16(ap1, bv[t][1], acc[s][t]);
            }
        }
    }

#pragma unroll
    for (int s = 0; s < 2; s++)
#pragma unroll
        for (int t = 0; t < 4; t++)
#pragma unroll
            for (int r = 0; r < 4; r++)
                Ctx[(size_t)(b * kS + qbase + s * 16 + quad * 4 + r) * kD + h * kDh + t * 16 + l16] =
                    f2b(acc[s][t][r]);
}

// ---------------------------------------------------------------------------
// K4: row LayerNorm
// ---------------------------------------------------------------------------
__global__ void ln_kernel(const float* __restrict__ R, const float* __restrict__ gamma,
                          const float* __restrict__ beta, float* __restrict__ out) {
    const int row = blockIdx.x;
    const int tid = threadIdx.x;
    const float4 v = ((const float4*)(R + (size_t)row * kD))[tid];
    float s  = v.x + v.y + v.z + v.w;
    float ss = v.x * v.x + v.y * v.y + v.z * v.z + v.w * v.w;
#pragma unroll
    for (int off = 32; off > 0; off >>= 1) {
        s  += __shfl_down(s, off, 64);
        ss += __shfl_down(ss, off, 64);
    }
    __shared__ float ws_s[4], ws_ss[4];
    __shared__ float mu_sh, inv_sh;
    const int lane = tid & 63, w = tid >> 6;
    if (lane == 0) { ws_s[w] = s; ws_ss[w] = ss; }
    __syncthreads();
    if (tid == 0) {
        float S1 = ws_s[0] + ws_s[1] + ws_s[2] + ws_s[3];
        float S2 = ws_ss[0] + ws_ss[1] + ws_ss[2] + ws_ss[3];
        float mu = S1 * (1.0f / kD);
        float var = S2 * (1.0f / kD) - mu * mu;
        mu_sh = mu;
        inv_sh = rsqrtf(var + 1e-5f);
    }
    __syncthreads();
    const float mu = mu_sh, inv = inv_sh;
    const float4 g  = ((const float4*)gamma)[tid];
    const float4 bb = ((const float4*)beta)[tid];
    float4 o;
    o.x = (v.x - mu) * inv * g.x + bb.x;
    o.y = (v.y - mu) * inv * g.y + bb.y;
    o.z = (v.z - mu) * inv * g.z + bb.z;
    o.w = (v.w - mu) * inv * g.w + bb.w;
    ((float4*)(out + (size_t)row * kD))[tid] = o;
}

// ---------------------------------------------------------------------------
// Workspace layout (64 MB peak, aliasing is stream-ordered-safe):
//   [0,   8MB)  Xb bf16
//   [8,  16MB)  Wb bf16 wq|wk|wv|wo
//   [16, 40MB)  QKV bf16 Q|K|V  (Q pre-scaled by 0.125*log2e)
//   [40, 48MB)  Ctx bf16
//   [48, 64MB)  VT bf16 [32][64][2048]; ALIASES R (written strictly later)
// ---------------------------------------------------------------------------
extern "C" void kernel_launch(void* const* d_in, const int* in_sizes, int n_in,
                              void* d_out, int out_size, void* d_ws, size_t ws_size,
                              hipStream_t stream) {
    const float* x     = (const float*)d_in[0];
    const float* wq    = (const float*)d_in[1];
    const float* wk    = (const float*)d_in[2];
    const float* wv    = (const float*)d_in[3];
    const float* wo    = (const float*)d_in[4];
    const float* gamma = (const float*)d_in[5];
    const float* beta  = (const float*)d_in[6];
    float* out = (float*)d_out;

    char* ws = (char*)d_ws;
    unsigned short* Xb  = (unsigned short*)(ws);
    unsigned short* Wb  = (unsigned short*)(ws + (8u  << 20));
    unsigned short* QKV = (unsigned short*)(ws + (16u << 20));
    unsigned short* Qb  = QKV;
    unsigned short* Kb  = QKV + (size_t)kBS * kD;
    unsigned short* Vb  = QKV + (size_t)2 * kBS * kD;
    unsigned short* Ctx = (unsigned short*)(ws + (40u << 20));
    unsigned short* VT  = (unsigned short*)(ws + (48u << 20));
    float* R            = (float*)(ws + (48u << 20));  // aliases VT

    convert_kernel<<<8192, 256, 0, stream>>>(x, wq, wk, wv, wo, Xb, Wb);

    gemm_nt<0><<<dim3(kD / 128, kBS / 128, 3), 256, 0, stream>>>(
        Xb, Wb, QKV, nullptr, kBS, kD, kD);

    stats_vt_kernel<<<2048, 64, 0, stream>>>(Qb, Kb, Vb, VT);

    ctx_kernel<<<2048, 64, 0, stream>>>(Qb, Kb, VT, Ctx);

    gemm_nt<1><<<dim3(kD / 128, kBS / 128, 1), 256, 0, stream>>>(
        Ctx, Wb + (size_t)3 * kD * kD, R, x, kBS, kD, kD);

    ln_kernel<<<kBS, 256, 0, stream>>>(R, gamma, beta, out);
}

// Round 12
// 271.705 us; speedup vs baseline: 1.1643x; 1.1643x over previous
//
#include <hip/hip_runtime.h>
#include <hip/hip_bf16.h>

// Problem constants
constexpr int kB   = 2;
constexpr int kS   = 2048;
constexpr int kD   = 1024;
constexpr int kH   = 16;
constexpr int kDh  = 64;
constexpr int kBS  = kB * kS;          // 4096 rows

typedef __attribute__((ext_vector_type(8))) short short8;   // 8 bf16 = 4 VGPRs
typedef __attribute__((ext_vector_type(4))) float floatx4;  // MFMA acc

__device__ inline unsigned short f2b(float f) {
    __hip_bfloat16 h = __float2bfloat16(f);
    return *reinterpret_cast<unsigned short*>(&h);
}

__device__ inline float b2f(unsigned short u) {
    union { unsigned u; float f; } cv;
    cv.u = (unsigned)u << 16;
    return cv.f;
}

__device__ inline floatx4 mfma16(short8 a, short8 b, floatx4 c) {
    return __builtin_amdgcn_mfma_f32_16x16x32_bf16(a, b, c, 0, 0, 0);
}

// async global->LDS, 16B per lane; LDS dest = wave-uniform base + lane*16
__device__ inline void gload16(const unsigned short* g, unsigned short* l) {
    __builtin_amdgcn_global_load_lds(
        (const __attribute__((address_space(1))) void*)g,
        (__attribute__((address_space(3))) void*)l, 16, 0, 0);
}

// ---------------------------------------------------------------------------
// K0: fp32 -> bf16 conversion of x (4M elems) and the 4 weights (4 x 1M elems)
// ---------------------------------------------------------------------------
__global__ void convert_kernel(const float* __restrict__ x,
                               const float* __restrict__ wq, const float* __restrict__ wk,
                               const float* __restrict__ wv, const float* __restrict__ wo,
                               unsigned short* __restrict__ xb, unsigned short* __restrict__ wb) {
    int gid = blockIdx.x * blockDim.x + threadIdx.x;
    long i4 = (long)gid * 4;
    const float* src;
    unsigned short* dst;
    long off;
    if (i4 < (long)kBS * kD) {
        src = x; dst = xb; off = i4;
    } else {
        long w = i4 - (long)kBS * kD;
        int sel = (int)(w >> 20);
        off = w & 1048575;
        src = (sel == 0) ? wq : (sel == 1) ? wk : (sel == 2) ? wv : wo;
        dst = wb + (long)sel * 1048576;
    }
    float4 v = *(const float4*)(src + off);
    ushort4 o;
    o.x = f2b(v.x); o.y = f2b(v.y); o.z = f2b(v.z); o.w = f2b(v.w);
    *(ushort4*)(dst + off) = o;
}

// ---------------------------------------------------------------------------
// K1: NT GEMM  C[M,N] = A[M,K] @ B[N,K]^T   (bf16 in, fp32 accum)
// m97-style staging: global_load_lds width=16, XOR-swizzled k-chunks.
// MODE 0: bf16 C; z==0 (Q) scaled by 0.125*log2(e) (exp2 domain).
// MODE 1: fp32 C + residual.
// ---------------------------------------------------------------------------
template <int MODE>
__launch_bounds__(256, 2)
__global__ void gemm_nt(const unsigned short* __restrict__ A,
                        const unsigned short* __restrict__ Bw,
                        void* __restrict__ Cout,
                        const float* __restrict__ resid,
                        int M, int N, int K) {
    __shared__ __align__(16) unsigned short As[128 * 32];
    __shared__ __align__(16) unsigned short Bs[128 * 32];

    const int z  = blockIdx.z;
    const unsigned short* Bp = Bw + (size_t)z * N * K;
    const int m0 = blockIdx.y * 128, n0 = blockIdx.x * 128;
    const int tid  = threadIdx.x;
    const int lane = tid & 63, wv = tid >> 6;
    const int wm = wv >> 1, wn = wv & 1;
    const int quad = lane >> 4, l16 = lane & 15;

    floatx4 acc[4][4] = {};

    const int c0 = wv * 64 + lane;          // 0..255   (rows 0..63)
    const int c1 = 256 + c0;                // 256..511 (rows 64..127)
    const int ar0 = c0 >> 2, aj0 = ((c0 & 3) ^ (ar0 & 3)) * 8;
    const int ar1 = c1 >> 2, aj1 = ((c1 & 3) ^ (ar1 & 3)) * 8;
    const unsigned short* Ag0 = A  + (size_t)(m0 + ar0) * K + aj0;
    const unsigned short* Ag1 = A  + (size_t)(m0 + ar1) * K + aj1;
    const unsigned short* Bg0 = Bp + (size_t)(n0 + ar0) * K + aj0;
    const unsigned short* Bg1 = Bp + (size_t)(n0 + ar1) * K + aj1;
    unsigned short* Asd0 = As + wv * 512;
    unsigned short* Asd1 = As + (4 + wv) * 512;
    unsigned short* Bsd0 = Bs + wv * 512;
    unsigned short* Bsd1 = Bs + (4 + wv) * 512;

    for (int k0 = 0; k0 < K; k0 += 32) {
        __syncthreads();
        gload16(Ag0 + k0, Asd0);
        gload16(Ag1 + k0, Asd1);
        gload16(Bg0 + k0, Bsd0);
        gload16(Bg1 + k0, Bsd1);
        __syncthreads();

        short8 af[4], bf[4];
#pragma unroll
        for (int i = 0; i < 4; i++) {
            const int R = wm * 64 + i * 16 + l16;
            af[i] = *(const short8*)(As + R * 32 + (quad ^ (l16 & 3)) * 8);
        }
#pragma unroll
        for (int j = 0; j < 4; j++) {
            const int R = wn * 64 + j * 16 + l16;
            bf[j] = *(const short8*)(Bs + R * 32 + (quad ^ (l16 & 3)) * 8);
        }
#pragma unroll
        for (int i = 0; i < 4; i++)
#pragma unroll
            for (int j = 0; j < 4; j++)
                acc[i][j] = mfma16(af[i], bf[j], acc[i][j]);
    }

#pragma unroll
    for (int i = 0; i < 4; i++)
#pragma unroll
        for (int j = 0; j < 4; j++) {
            const int row = m0 + wm * 64 + i * 16 + quad * 4;
            const int col = n0 + wn * 64 + j * 16 + l16;
#pragma unroll
            for (int r = 0; r < 4; r++) {
                float v = acc[i][j][r];
                if (MODE == 0) {
                    if (z == 0) v *= 0.18033688f;   // 0.125 * log2(e)
                    ((unsigned short*)Cout)[(size_t)z * M * N + (size_t)(row + r) * N + col] = f2b(v);
                } else {
                    size_t idx = (size_t)(row + r) * N + col;
                    ((float*)Cout)[idx] = v + resid[idx];
                }
            }
        }
}

// ---------------------------------------------------------------------------
// K2: FUSED column-softmax denominators + scaled V^T production (round 7).
// Phase 1: invl[k] = 1/sum_q exp2(s[q,k]) for this block's 64 keys
//   (K-stationary, Q staged via global_load_lds, XCD-swizzled bh decode).
// Phase 2: VT[bh][d][k] = V[b][k][h*64+d] * invl[k], invl via LDS broadcast.
// ---------------------------------------------------------------------------
__launch_bounds__(128, 3)
__global__ void stats_vt_kernel(const unsigned short* __restrict__ Qb,
                                const unsigned short* __restrict__ Kb,
                                const unsigned short* __restrict__ Vb,
                                unsigned short* __restrict__ VT) {
    __shared__ __align__(16) unsigned short Qs[64 * 68];  // staging (64) / transpose tile (65)
    __shared__ float s_inv[64];

    const int id = blockIdx.x;                       // 0..1023
    const int bh = (id & 7) + 8 * ((id >> 3) & 3);   // XCD-grouped
    const int keyblk = id >> 5;                      // 0..31
    const int b = bh >> 4, h = bh & 15;
    const int tid = threadIdx.x, lane = tid & 63, w = tid >> 6;   // w = 0..1
    const int quad = lane >> 4, l16 = lane & 15;
    const int keybase = keyblk * 64 + w * 32;

    short8 ak[2][2];
#pragma unroll
    for (int s = 0; s < 2; s++) {
        const unsigned short* Krow = Kb + (size_t)(b * kS + keybase + s * 16 + l16) * kD + h * kDh;
        ak[s][0] = *(const short8*)(Krow + quad * 8);
        ak[s][1] = *(const short8*)(Krow + 32 + quad * 8);
    }

    const int r0 = lane >> 3;
    const int jc = ((lane & 7) ^ r0) * 8;
    const unsigned short* Qg[4];
    unsigned short* Ql[4];
#pragma unroll
    for (int seg = 0; seg < 4; seg++) {
        const int row = seg * 16 + w * 8 + r0;              // 0..63
        Qg[seg] = Qb + (size_t)(b * kS + row) * kD + h * kDh + jc;   // + q0*kD per chunk
        Ql[seg] = Qs + (seg * 16 + w * 8) * 64;             // wave-uniform
    }

    const int pk0 = (quad ^ (l16 & 7)) * 8;
    const int pk1 = ((4 + quad) ^ (l16 & 7)) * 8;

    float lacc[2][4] = {};

    for (int q0 = 0; q0 < kS; q0 += 64) {
        __syncthreads();
#pragma unroll
        for (int seg = 0; seg < 4; seg++)
            gload16(Qg[seg] + (size_t)q0 * kD, Ql[seg]);
        __syncthreads();

#pragma unroll
        for (int c = 0; c < 4; c++) {
            const unsigned short* row = Qs + (c * 16 + l16) * 64;
            short8 bq0 = *(const short8*)(row + pk0);
            short8 bq1 = *(const short8*)(row + pk1);
#pragma unroll
            for (int s = 0; s < 2; s++) {
                floatx4 t = {0.f, 0.f, 0.f, 0.f};
                t = mfma16(ak[s][0], bq0, t);
                t = mfma16(ak[s][1], bq1, t);
#pragma unroll
                for (int r = 0; r < 4; r++)
                    lacc[s][r] += exp2f(t[r]);
            }
        }
    }

#pragma unroll
    for (int off = 1; off <= 8; off <<= 1)
#pragma unroll
        for (int s = 0; s < 2; s++)
#pragma unroll
            for (int r = 0; r < 4; r++)
                lacc[s][r] += __shfl_xor(lacc[s][r], off, 64);

    __syncthreads();   // Qs reads done before tile reuse; also orders s_inv
    if (l16 == 0) {
#pragma unroll
        for (int s = 0; s < 2; s++)
#pragma unroll
            for (int r = 0; r < 4; r++)
                s_inv[w * 32 + s * 16 + quad * 4 + r] = 1.0f / lacc[s][r];
    }
    __syncthreads();

    unsigned short* tile = Qs;   // reuse, stride 65
    {
        const int kr = tid >> 1, dc = (tid & 1) * 32;
        const float iv = s_inv[kr];
        const unsigned short* src = Vb + (size_t)(b * kS + keyblk * 64 + kr) * kD + h * kDh + dc;
        unsigned short vs[32];
        *(uint4*)(vs)      = *(const uint4*)(src);
        *(uint4*)(vs + 8)  = *(const uint4*)(src + 8);
        *(uint4*)(vs + 16) = *(const uint4*)(src + 16);
        *(uint4*)(vs + 24) = *(const uint4*)(src + 24);
#pragma unroll
        for (int i = 0; i < 32; i++)
            tile[kr * 65 + dc + i] = f2b(b2f(vs[i]) * iv);
    }
    __syncthreads();
    {
        const int d = tid >> 1, kc = (tid & 1) * 32;
        unsigned short os[32];
#pragma unroll
        for (int j = 0; j < 32; j++) os[j] = tile[(kc + j) * 65 + d];
        unsigned short* dst = VT + (size_t)bh * kDh * kS + (size_t)d * kS + keyblk * 64 + kc;
        *(uint4*)(dst)      = *(uint4*)(os);
        *(uint4*)(dst + 8)  = *(uint4*)(os + 8);
        *(uint4*)(dst + 16) = *(uint4*)(os + 16);
        *(uint4*)(dst + 24) = *(uint4*)(os + 24);
    }
}

// ---------------------------------------------------------------------------
// K3: ctx = exp2(S) @ VT^T — round-7 base + S^T operand swap (round 12).
// Block = 128 threads (2 waves x 32 q); grid 1024, XCD-swizzled. Per 64-key
// chunk: stage K-tile + VT-tile via global_load_lds w=16 (XOR chunk swizzle).
// S computed TRANSPOSED (mfma(bk, aq) -> D[key][q]; A/B frag layouts are
// identical so staged reads are unchanged). Each lane's 4 acc values are 4
// consecutive k for fixed q -> ONE packed ds_write_b64 per (s,c): 8 b64
// writes/wave-chunk replace 32 scalar b16 writes. P layout [q][k] stride 72
// with 16-block XOR swizzle keyed on q&3 (consistent on write + b128 read).
// ---------------------------------------------------------------------------
__launch_bounds__(128, 3)
__global__ void ctx_kernel(const unsigned short* __restrict__ Qb,
                           const unsigned short* __restrict__ Kb,
                           const unsigned short* __restrict__ VT,
                           unsigned short* __restrict__ Ctx) {
    constexpr int LDP = 72;
    __shared__ __align__(16) unsigned short Ks[64 * 64];
    __shared__ __align__(16) unsigned short VTs[64 * 64];
    __shared__ __align__(16) unsigned short Pt[2][32 * LDP];

    const int id = blockIdx.x;                       // 0..1023
    const int bh = (id & 7) + 8 * ((id >> 3) & 3);   // XCD-grouped
    const int qblk = id >> 5;                        // 0..31
    const int b = bh >> 4, h = bh & 15;
    const int tid = threadIdx.x, lane = tid & 63, w = tid >> 6;   // w = 0..1
    const int quad = lane >> 4, l16 = lane & 15;
    const int qbase = qblk * 64 + w * 32;

    short8 aq[2][2];
#pragma unroll
    for (int s = 0; s < 2; s++) {
        const unsigned short* Qrow = Qb + (size_t)(b * kS + qbase + s * 16 + l16) * kD + h * kDh;
        aq[s][0] = *(const short8*)(Qrow + quad * 8);
        aq[s][1] = *(const short8*)(Qrow + 32 + quad * 8);
    }
    floatx4 acc[2][4] = {};

    const unsigned short* Kbase = Kb + (size_t)(b * kS) * kD + h * kDh;
    const unsigned short* VTb   = VT + (size_t)bh * kDh * kS;

    const int r0 = lane >> 3;
    const int jc = ((lane & 7) ^ r0) * 8;
    const unsigned short* Kg[4];
    const unsigned short* Vg[4];
    unsigned short* Kl[4];
    unsigned short* Vl[4];
#pragma unroll
    for (int seg = 0; seg < 4; seg++) {
        const int row = seg * 16 + w * 8 + r0;         // 0..63
        Kg[seg] = Kbase + (size_t)row * kD + jc;       // + k0*kD per chunk
        Vg[seg] = VTb + (size_t)row * kS + jc;         // + k0 per chunk
        Kl[seg] = Ks  + (seg * 16 + w * 8) * 64;       // wave-uniform
        Vl[seg] = VTs + (seg * 16 + w * 8) * 64;
    }

    unsigned short* P = Pt[w];
    // P[q][k] stride LDP; physical 16-block kp = (k>>4) ^ (q&3).
    // Write (lane q=l16, keys c*16+quad*4..+3): one b64 at
    //   l16*LDP + ((c^(l16&3))*16 + quad*4)   [+ s*16*LDP]
    unsigned short* pw[4];
#pragma unroll
    for (int c = 0; c < 4; c++)
        pw[c] = P + l16 * LDP + ((c ^ (l16 & 3)) * 16) + quad * 4;
    // Read (A-frag, lane q=l16, k=h2*32+quad*8..+7): b128 at
    //   l16*LDP + (((h2*2+(quad>>1)) ^ (l16&3))*16 + (quad&1)*8)  [+ s*16*LDP]
    const unsigned short* pr[2];
#pragma unroll
    for (int h2 = 0; h2 < 2; h2++)
        pr[h2] = P + l16 * LDP + (((h2 * 2 + (quad >> 1)) ^ (l16 & 3)) * 16) + (quad & 1) * 8;

    const int pk0 = (quad ^ (l16 & 7)) * 8;
    const int pk1 = ((4 + quad) ^ (l16 & 7)) * 8;

    for (int k0 = 0; k0 < kS; k0 += 64) {
        __syncthreads();
#pragma unroll
        for (int seg = 0; seg < 4; seg++) {
            gload16(Kg[seg] + (size_t)k0 * kD, Kl[seg]);
            gload16(Vg[seg] + k0, Vl[seg]);
        }
        __syncthreads();

        short8 bk[4][2];
#pragma unroll
        for (int c = 0; c < 4; c++) {
            const unsigned short* row = Ks + (c * 16 + l16) * 64;
            bk[c][0] = *(const short8*)(row + pk0);
            bk[c][1] = *(const short8*)(row + pk1);
        }
        // S^T tiles: mfma(A=K-frag, B=Q-frag) -> D[key][q]
        floatx4 sc[2][4];
#pragma unroll
        for (int s = 0; s < 2; s++)
#pragma unroll
            for (int c = 0; c < 4; c++) {
                floatx4 t = {0.f, 0.f, 0.f, 0.f};
                t = mfma16(bk[c][0], aq[s][0], t);
                sc[s][c] = mfma16(bk[c][1], aq[s][1], t);
            }
        // exp2 -> packed truncating bf16 -> one b64 per (s,c)
#pragma unroll
        for (int s = 0; s < 2; s++)
#pragma unroll
            for (int c = 0; c < 4; c++) {
                union { float f; unsigned u; } e0, e1, e2, e3;
                e0.f = exp2f(sc[s][c][0]);
                e1.f = exp2f(sc[s][c][1]);
                e2.f = exp2f(sc[s][c][2]);
                e3.f = exp2f(sc[s][c][3]);
                uint2 pk;
                pk.x = (e0.u >> 16) | (e1.u & 0xffff0000u);
                pk.y = (e2.u >> 16) | (e3.u & 0xffff0000u);
                *(uint2*)(pw[c] + s * 16 * LDP) = pk;
            }

        short8 bv[4][2];
#pragma unroll
        for (int t = 0; t < 4; t++) {
            const unsigned short* row = VTs + (t * 16 + l16) * 64;
            bv[t][0] = *(const short8*)(row + pk0);
            bv[t][1] = *(const short8*)(row + pk1);
        }
#pragma unroll
        for (int s = 0; s < 2; s++) {
            short8 ap0 = *(const short8*)(pr[0] + s * 16 * LDP);
            short8 ap1 = *(const short8*)(pr[1] + s * 16 * LDP);
#pragma unroll
            for (int t = 0; t < 4; t++) {
                acc[s][t] = mfma16(ap0, bv[t][0], acc[s][t]);
                acc[s][t] = mfma16(ap1, bv[t][1], acc[s][t]);
            }
        }
    }

#pragma unroll
    for (int s = 0; s < 2; s++)
#pragma unroll
        for (int t = 0; t < 4; t++)
#pragma unroll
            for (int r = 0; r < 4; r++)
                Ctx[(size_t)(b * kS + qbase + s * 16 + quad * 4 + r) * kD + h * kDh + t * 16 + l16] =
                    f2b(acc[s][t][r]);
}

// ---------------------------------------------------------------------------
// K4: row LayerNorm
// ---------------------------------------------------------------------------
__global__ void ln_kernel(const float* __restrict__ R, const float* __restrict__ gamma,
                          const float* __restrict__ beta, float* __restrict__ out) {
    const int row = blockIdx.x;
    const int tid = threadIdx.x;
    const float4 v = ((const float4*)(R + (size_t)row * kD))[tid];
    float s  = v.x + v.y + v.z + v.w;
    float ss = v.x * v.x + v.y * v.y + v.z * v.z + v.w * v.w;
#pragma unroll
    for (int off = 32; off > 0; off >>= 1) {
        s  += __shfl_down(s, off, 64);
        ss += __shfl_down(ss, off, 64);
    }
    __shared__ float ws_s[4], ws_ss[4];
    __shared__ float mu_sh, inv_sh;
    const int lane = tid & 63, w = tid >> 6;
    if (lane == 0) { ws_s[w] = s; ws_ss[w] = ss; }
    __syncthreads();
    if (tid == 0) {
        float S1 = ws_s[0] + ws_s[1] + ws_s[2] + ws_s[3];
        float S2 = ws_ss[0] + ws_ss[1] + ws_ss[2] + ws_ss[3];
        float mu = S1 * (1.0f / kD);
        float var = S2 * (1.0f / kD) - mu * mu;
        mu_sh = mu;
        inv_sh = rsqrtf(var + 1e-5f);
    }
    __syncthreads();
    const float mu = mu_sh, inv = inv_sh;
    const float4 g  = ((const float4*)gamma)[tid];
    const float4 bb = ((const float4*)beta)[tid];
    float4 o;
    o.x = (v.x - mu) * inv * g.x + bb.x;
    o.y = (v.y - mu) * inv * g.y + bb.y;
    o.z = (v.z - mu) * inv * g.z + bb.z;
    o.w = (v.w - mu) * inv * g.w + bb.w;
    ((float4*)(out + (size_t)row * kD))[tid] = o;
}

// ---------------------------------------------------------------------------
// Workspace layout (64 MB peak, aliasing is stream-ordered-safe):
//   [0,   8MB)  Xb bf16
//   [8,  16MB)  Wb bf16 wq|wk|wv|wo
//   [16, 40MB)  QKV bf16 Q|K|V  (Q pre-scaled by 0.125*log2e)
//   [40, 48MB)  Ctx bf16
//   [48, 64MB)  VT bf16 [32][64][2048]; ALIASES R (written strictly later)
// ---------------------------------------------------------------------------
extern "C" void kernel_launch(void* const* d_in, const int* in_sizes, int n_in,
                              void* d_out, int out_size, void* d_ws, size_t ws_size,
                              hipStream_t stream) {
    const float* x     = (const float*)d_in[0];
    const float* wq    = (const float*)d_in[1];
    const float* wk    = (const float*)d_in[2];
    const float* wv    = (const float*)d_in[3];
    const float* wo    = (const float*)d_in[4];
    const float* gamma = (const float*)d_in[5];
    const float* beta  = (const float*)d_in[6];
    float* out = (float*)d_out;

    char* ws = (char*)d_ws;
    unsigned short* Xb  = (unsigned short*)(ws);
    unsigned short* Wb  = (unsigned short*)(ws + (8u  << 20));
    unsigned short* QKV = (unsigned short*)(ws + (16u << 20));
    unsigned short* Qb  = QKV;
    unsigned short* Kb  = QKV + (size_t)kBS * kD;
    unsigned short* Vb  = QKV + (size_t)2 * kBS * kD;
    unsigned short* Ctx = (unsigned short*)(ws + (40u << 20));
    unsigned short* VT  = (unsigned short*)(ws + (48u << 20));
    float* R            = (float*)(ws + (48u << 20));  // aliases VT

    convert_kernel<<<8192, 256, 0, stream>>>(x, wq, wk, wv, wo, Xb, Wb);

    gemm_nt<0><<<dim3(kD / 128, kBS / 128, 3), 256, 0, stream>>>(
        Xb, Wb, QKV, nullptr, kBS, kD, kD);

    stats_vt_kernel<<<1024, 128, 0, stream>>>(Qb, Kb, Vb, VT);

    ctx_kernel<<<1024, 128, 0, stream>>>(Qb, Kb, VT, Ctx);

    gemm_nt<1><<<dim3(kD / 128, kBS / 128, 1), 256, 0, stream>>>(
        Ctx, Wb + (size_t)3 * kD * kD, R, x, kBS, kD, kD);

    ln_kernel<<<kBS, 256, 0, stream>>>(R, gamma, beta, out);
}

// Round 13
// 263.810 us; speedup vs baseline: 1.1992x; 1.0299x over previous
//
#include <hip/hip_runtime.h>
#include <hip/hip_bf16.h>

// Problem constants
constexpr int kB   = 2;
constexpr int kS   = 2048;
constexpr int kD   = 1024;
constexpr int kH   = 16;
constexpr int kDh  = 64;
constexpr int kBS  = kB * kS;          // 4096 rows

typedef __attribute__((ext_vector_type(8))) short short8;   // 8 bf16 = 4 VGPRs
typedef __attribute__((ext_vector_type(4))) float floatx4;  // MFMA acc

__device__ inline unsigned short f2b(float f) {
    __hip_bfloat16 h = __float2bfloat16(f);
    return *reinterpret_cast<unsigned short*>(&h);
}

__device__ inline float b2f(unsigned short u) {
    union { unsigned u; float f; } cv;
    cv.u = (unsigned)u << 16;
    return cv.f;
}

__device__ inline floatx4 mfma16(short8 a, short8 b, floatx4 c) {
    return __builtin_amdgcn_mfma_f32_16x16x32_bf16(a, b, c, 0, 0, 0);
}

// async global->LDS, 16B per lane; LDS dest = wave-uniform base + lane*16
__device__ inline void gload16(const unsigned short* g, unsigned short* l) {
    __builtin_amdgcn_global_load_lds(
        (const __attribute__((address_space(1))) void*)g,
        (__attribute__((address_space(3))) void*)l, 16, 0, 0);
}

// ---------------------------------------------------------------------------
// K0: fp32 -> bf16 conversion of x (4M elems) and the 4 weights (4 x 1M elems)
// ---------------------------------------------------------------------------
__global__ void convert_kernel(const float* __restrict__ x,
                               const float* __restrict__ wq, const float* __restrict__ wk,
                               const float* __restrict__ wv, const float* __restrict__ wo,
                               unsigned short* __restrict__ xb, unsigned short* __restrict__ wb) {
    int gid = blockIdx.x * blockDim.x + threadIdx.x;
    long i4 = (long)gid * 4;
    const float* src;
    unsigned short* dst;
    long off;
    if (i4 < (long)kBS * kD) {
        src = x; dst = xb; off = i4;
    } else {
        long w = i4 - (long)kBS * kD;
        int sel = (int)(w >> 20);
        off = w & 1048575;
        src = (sel == 0) ? wq : (sel == 1) ? wk : (sel == 2) ? wv : wo;
        dst = wb + (long)sel * 1048576;
    }
    float4 v = *(const float4*)(src + off);
    ushort4 o;
    o.x = f2b(v.x); o.y = f2b(v.y); o.z = f2b(v.z); o.w = f2b(v.w);
    *(ushort4*)(dst + off) = o;
}

// ---------------------------------------------------------------------------
// K1: NT GEMM  C[M,N] = A[M,K] @ B[N,K]^T   (bf16 in, fp32 accum)
// Round 13: BK=64 — 32 MFMAs per barrier-pair (was 16), halving the
// vmcnt(0)+s_barrier drains. Staging via global_load_lds w=16 with the
// 8-chunk XOR swizzle (same pattern as ctx staging); 32 KB LDS, 2 blocks/CU.
// MODE 0: bf16 C; z==0 (Q) scaled by 0.125*log2(e) (exp2 domain).
// MODE 1: fp32 C + residual.
// ---------------------------------------------------------------------------
template <int MODE>
__launch_bounds__(256, 2)
__global__ void gemm_nt(const unsigned short* __restrict__ A,
                        const unsigned short* __restrict__ Bw,
                        void* __restrict__ Cout,
                        const float* __restrict__ resid,
                        int M, int N, int K) {
    __shared__ __align__(16) unsigned short As[128 * 64];
    __shared__ __align__(16) unsigned short Bs[128 * 64];

    const int z  = blockIdx.z;
    const unsigned short* Bp = Bw + (size_t)z * N * K;
    const int m0 = blockIdx.y * 128, n0 = blockIdx.x * 128;
    const int tid  = threadIdx.x;
    const int lane = tid & 63, wv = tid >> 6;
    const int wm = wv >> 1, wn = wv & 1;
    const int quad = lane >> 4, l16 = lane & 15;

    floatx4 acc[4][4] = {};

    // staging: wave w covers 4 bands of 8 rows (band = seg*32 + w*8);
    // lane covers row r0 = lane>>3 in band, physical chunk lane&7 holding
    // logical chunk (lane&7)^r0 (8-chunk XOR swizzle on 64-short rows)
    const int r0 = lane >> 3;
    const int jc = ((lane & 7) ^ r0) * 8;
    const unsigned short* Ag[4];
    const unsigned short* Bg[4];
    unsigned short* Asd[4];
    unsigned short* Bsd[4];
#pragma unroll
    for (int seg = 0; seg < 4; seg++) {
        const int row = seg * 32 + wv * 8 + r0;        // 0..127
        Ag[seg] = A  + (size_t)(m0 + row) * K + jc;    // + k0 per iter
        Bg[seg] = Bp + (size_t)(n0 + row) * K + jc;
        Asd[seg] = As + (seg * 32 + wv * 8) * 64;      // wave-uniform
        Bsd[seg] = Bs + (seg * 32 + wv * 8) * 64;
    }

    // frag-read physical chunk offsets for the two 32-col halves
    const int pk0 = (quad ^ (l16 & 7)) * 8;        // logical chunk quad
    const int pk1 = ((4 + quad) ^ (l16 & 7)) * 8;  // logical chunk 4+quad

    for (int k0 = 0; k0 < K; k0 += 64) {
        __syncthreads();
#pragma unroll
        for (int seg = 0; seg < 4; seg++) {
            gload16(Ag[seg] + k0, Asd[seg]);
            gload16(Bg[seg] + k0, Bsd[seg]);
        }
        __syncthreads();

#pragma unroll
        for (int h = 0; h < 2; h++) {
            const int pk = h ? pk1 : pk0;
            short8 af[4], bf[4];
#pragma unroll
            for (int i = 0; i < 4; i++)
                af[i] = *(const short8*)(As + (wm * 64 + i * 16 + l16) * 64 + pk);
#pragma unroll
            for (int j = 0; j < 4; j++)
                bf[j] = *(const short8*)(Bs + (wn * 64 + j * 16 + l16) * 64 + pk);
#pragma unroll
            for (int i = 0; i < 4; i++)
#pragma unroll
                for (int j = 0; j < 4; j++)
                    acc[i][j] = mfma16(af[i], bf[j], acc[i][j]);
        }
    }

#pragma unroll
    for (int i = 0; i < 4; i++)
#pragma unroll
        for (int j = 0; j < 4; j++) {
            const int row = m0 + wm * 64 + i * 16 + quad * 4;
            const int col = n0 + wn * 64 + j * 16 + l16;
#pragma unroll
            for (int r = 0; r < 4; r++) {
                float v = acc[i][j][r];
                if (MODE == 0) {
                    if (z == 0) v *= 0.18033688f;   // 0.125 * log2(e)
                    ((unsigned short*)Cout)[(size_t)z * M * N + (size_t)(row + r) * N + col] = f2b(v);
                } else {
                    size_t idx = (size_t)(row + r) * N + col;
                    ((float*)Cout)[idx] = v + resid[idx];
                }
            }
        }
}

// ---------------------------------------------------------------------------
// K2: FUSED column-softmax denominators + scaled V^T production (round 7).
// Phase 1: invl[k] = 1/sum_q exp2(s[q,k]) for this block's 64 keys
//   (K-stationary, Q staged via global_load_lds, XCD-swizzled bh decode).
// Phase 2: VT[bh][d][k] = V[b][k][h*64+d] * invl[k], invl via LDS broadcast.
// ---------------------------------------------------------------------------
__launch_bounds__(128, 3)
__global__ void stats_vt_kernel(const unsigned short* __restrict__ Qb,
                                const unsigned short* __restrict__ Kb,
                                const unsigned short* __restrict__ Vb,
                                unsigned short* __restrict__ VT) {
    __shared__ __align__(16) unsigned short Qs[64 * 68];  // staging (64) / transpose tile (65)
    __shared__ float s_inv[64];

    const int id = blockIdx.x;                       // 0..1023
    const int bh = (id & 7) + 8 * ((id >> 3) & 3);   // XCD-grouped
    const int keyblk = id >> 5;                      // 0..31
    const int b = bh >> 4, h = bh & 15;
    const int tid = threadIdx.x, lane = tid & 63, w = tid >> 6;   // w = 0..1
    const int quad = lane >> 4, l16 = lane & 15;
    const int keybase = keyblk * 64 + w * 32;

    short8 ak[2][2];
#pragma unroll
    for (int s = 0; s < 2; s++) {
        const unsigned short* Krow = Kb + (size_t)(b * kS + keybase + s * 16 + l16) * kD + h * kDh;
        ak[s][0] = *(const short8*)(Krow + quad * 8);
        ak[s][1] = *(const short8*)(Krow + 32 + quad * 8);
    }

    const int r0 = lane >> 3;
    const int jc = ((lane & 7) ^ r0) * 8;
    const unsigned short* Qg[4];
    unsigned short* Ql[4];
#pragma unroll
    for (int seg = 0; seg < 4; seg++) {
        const int row = seg * 16 + w * 8 + r0;              // 0..63
        Qg[seg] = Qb + (size_t)(b * kS + row) * kD + h * kDh + jc;   // + q0*kD per chunk
        Ql[seg] = Qs + (seg * 16 + w * 8) * 64;             // wave-uniform
    }

    const int pk0 = (quad ^ (l16 & 7)) * 8;
    const int pk1 = ((4 + quad) ^ (l16 & 7)) * 8;

    float lacc[2][4] = {};

    for (int q0 = 0; q0 < kS; q0 += 64) {
        __syncthreads();
#pragma unroll
        for (int seg = 0; seg < 4; seg++)
            gload16(Qg[seg] + (size_t)q0 * kD, Ql[seg]);
        __syncthreads();

#pragma unroll
        for (int c = 0; c < 4; c++) {
            const unsigned short* row = Qs + (c * 16 + l16) * 64;
            short8 bq0 = *(const short8*)(row + pk0);
            short8 bq1 = *(const short8*)(row + pk1);
#pragma unroll
            for (int s = 0; s < 2; s++) {
                floatx4 t = {0.f, 0.f, 0.f, 0.f};
                t = mfma16(ak[s][0], bq0, t);
                t = mfma16(ak[s][1], bq1, t);
#pragma unroll
                for (int r = 0; r < 4; r++)
                    lacc[s][r] += exp2f(t[r]);
            }
        }
    }

#pragma unroll
    for (int off = 1; off <= 8; off <<= 1)
#pragma unroll
        for (int s = 0; s < 2; s++)
#pragma unroll
            for (int r = 0; r < 4; r++)
                lacc[s][r] += __shfl_xor(lacc[s][r], off, 64);

    __syncthreads();   // Qs reads done before tile reuse; also orders s_inv
    if (l16 == 0) {
#pragma unroll
        for (int s = 0; s < 2; s++)
#pragma unroll
            for (int r = 0; r < 4; r++)
                s_inv[w * 32 + s * 16 + quad * 4 + r] = 1.0f / lacc[s][r];
    }
    __syncthreads();

    unsigned short* tile = Qs;   // reuse, stride 65
    {
        const int kr = tid >> 1, dc = (tid & 1) * 32;
        const float iv = s_inv[kr];
        const unsigned short* src = Vb + (size_t)(b * kS + keyblk * 64 + kr) * kD + h * kDh + dc;
        unsigned short vs[32];
        *(uint4*)(vs)      = *(const uint4*)(src);
        *(uint4*)(vs + 8)  = *(const uint4*)(src + 8);
        *(uint4*)(vs + 16) = *(const uint4*)(src + 16);
        *(uint4*)(vs + 24) = *(const uint4*)(src + 24);
#pragma unroll
        for (int i = 0; i < 32; i++)
            tile[kr * 65 + dc + i] = f2b(b2f(vs[i]) * iv);
    }
    __syncthreads();
    {
        const int d = tid >> 1, kc = (tid & 1) * 32;
        unsigned short os[32];
#pragma unroll
        for (int j = 0; j < 32; j++) os[j] = tile[(kc + j) * 65 + d];
        unsigned short* dst = VT + (size_t)bh * kDh * kS + (size_t)d * kS + keyblk * 64 + kc;
        *(uint4*)(dst)      = *(uint4*)(os);
        *(uint4*)(dst + 8)  = *(uint4*)(os + 8);
        *(uint4*)(dst + 16) = *(uint4*)(os + 16);
        *(uint4*)(dst + 24) = *(uint4*)(os + 24);
    }
}

// ---------------------------------------------------------------------------
// K3: ctx = exp2(S) @ VT^T — round-12 best (S^T operand swap, packed b64 P).
// Block = 128 threads (2 waves x 32 q); grid 1024, XCD-swizzled.
// ---------------------------------------------------------------------------
__launch_bounds__(128, 3)
__global__ void ctx_kernel(const unsigned short* __restrict__ Qb,
                           const unsigned short* __restrict__ Kb,
                           const unsigned short* __restrict__ VT,
                           unsigned short* __restrict__ Ctx) {
    constexpr int LDP = 72;
    __shared__ __align__(16) unsigned short Ks[64 * 64];
    __shared__ __align__(16) unsigned short VTs[64 * 64];
    __shared__ __align__(16) unsigned short Pt[2][32 * LDP];

    const int id = blockIdx.x;                       // 0..1023
    const int bh = (id & 7) + 8 * ((id >> 3) & 3);   // XCD-grouped
    const int qblk = id >> 5;                        // 0..31
    const int b = bh >> 4, h = bh & 15;
    const int tid = threadIdx.x, lane = tid & 63, w = tid >> 6;   // w = 0..1
    const int quad = lane >> 4, l16 = lane & 15;
    const int qbase = qblk * 64 + w * 32;

    short8 aq[2][2];
#pragma unroll
    for (int s = 0; s < 2; s++) {
        const unsigned short* Qrow = Qb + (size_t)(b * kS + qbase + s * 16 + l16) * kD + h * kDh;
        aq[s][0] = *(const short8*)(Qrow + quad * 8);
        aq[s][1] = *(const short8*)(Qrow + 32 + quad * 8);
    }
    floatx4 acc[2][4] = {};

    const unsigned short* Kbase = Kb + (size_t)(b * kS) * kD + h * kDh;
    const unsigned short* VTb   = VT + (size_t)bh * kDh * kS;

    const int r0 = lane >> 3;
    const int jc = ((lane & 7) ^ r0) * 8;
    const unsigned short* Kg[4];
    const unsigned short* Vg[4];
    unsigned short* Kl[4];
    unsigned short* Vl[4];
#pragma unroll
    for (int seg = 0; seg < 4; seg++) {
        const int row = seg * 16 + w * 8 + r0;         // 0..63
        Kg[seg] = Kbase + (size_t)row * kD + jc;       // + k0*kD per chunk
        Vg[seg] = VTb + (size_t)row * kS + jc;         // + k0 per chunk
        Kl[seg] = Ks  + (seg * 16 + w * 8) * 64;       // wave-uniform
        Vl[seg] = VTs + (seg * 16 + w * 8) * 64;
    }

    unsigned short* P = Pt[w];
    // P[q][k] stride LDP; physical 16-block kp = (k>>4) ^ (q&3).
    unsigned short* pw[4];
#pragma unroll
    for (int c = 0; c < 4; c++)
        pw[c] = P + l16 * LDP + ((c ^ (l16 & 3)) * 16) + quad * 4;
    const unsigned short* pr[2];
#pragma unroll
    for (int h2 = 0; h2 < 2; h2++)
        pr[h2] = P + l16 * LDP + (((h2 * 2 + (quad >> 1)) ^ (l16 & 3)) * 16) + (quad & 1) * 8;

    const int pk0 = (quad ^ (l16 & 7)) * 8;
    const int pk1 = ((4 + quad) ^ (l16 & 7)) * 8;

    for (int k0 = 0; k0 < kS; k0 += 64) {
        __syncthreads();
#pragma unroll
        for (int seg = 0; seg < 4; seg++) {
            gload16(Kg[seg] + (size_t)k0 * kD, Kl[seg]);
            gload16(Vg[seg] + k0, Vl[seg]);
        }
        __syncthreads();

        short8 bk[4][2];
#pragma unroll
        for (int c = 0; c < 4; c++) {
            const unsigned short* row = Ks + (c * 16 + l16) * 64;
            bk[c][0] = *(const short8*)(row + pk0);
            bk[c][1] = *(const short8*)(row + pk1);
        }
        // S^T tiles: mfma(A=K-frag, B=Q-frag) -> D[key][q]
        floatx4 sc[2][4];
#pragma unroll
        for (int s = 0; s < 2; s++)
#pragma unroll
            for (int c = 0; c < 4; c++) {
                floatx4 t = {0.f, 0.f, 0.f, 0.f};
                t = mfma16(bk[c][0], aq[s][0], t);
                sc[s][c] = mfma16(bk[c][1], aq[s][1], t);
            }
        // exp2 -> packed truncating bf16 -> one b64 per (s,c)
#pragma unroll
        for (int s = 0; s < 2; s++)
#pragma unroll
            for (int c = 0; c < 4; c++) {
                union { float f; unsigned u; } e0, e1, e2, e3;
                e0.f = exp2f(sc[s][c][0]);
                e1.f = exp2f(sc[s][c][1]);
                e2.f = exp2f(sc[s][c][2]);
                e3.f = exp2f(sc[s][c][3]);
                uint2 pk;
                pk.x = (e0.u >> 16) | (e1.u & 0xffff0000u);
                pk.y = (e2.u >> 16) | (e3.u & 0xffff0000u);
                *(uint2*)(pw[c] + s * 16 * LDP) = pk;
            }

        short8 bv[4][2];
#pragma unroll
        for (int t = 0; t < 4; t++) {
            const unsigned short* row = VTs + (t * 16 + l16) * 64;
            bv[t][0] = *(const short8*)(row + pk0);
            bv[t][1] = *(const short8*)(row + pk1);
        }
#pragma unroll
        for (int s = 0; s < 2; s++) {
            short8 ap0 = *(const short8*)(pr[0] + s * 16 * LDP);
            short8 ap1 = *(const short8*)(pr[1] + s * 16 * LDP);
#pragma unroll
            for (int t = 0; t < 4; t++) {
                acc[s][t] = mfma16(ap0, bv[t][0], acc[s][t]);
                acc[s][t] = mfma16(ap1, bv[t][1], acc[s][t]);
            }
        }
    }

#pragma unroll
    for (int s = 0; s < 2; s++)
#pragma unroll
        for (int t = 0; t < 4; t++)
#pragma unroll
            for (int r = 0; r < 4; r++)
                Ctx[(size_t)(b * kS + qbase + s * 16 + quad * 4 + r) * kD + h * kDh + t * 16 + l16] =
                    f2b(acc[s][t][r]);
}

// ---------------------------------------------------------------------------
// K4: row LayerNorm
// ---------------------------------------------------------------------------
__global__ void ln_kernel(const float* __restrict__ R, const float* __restrict__ gamma,
                          const float* __restrict__ beta, float* __restrict__ out) {
    const int row = blockIdx.x;
    const int tid = threadIdx.x;
    const float4 v = ((const float4*)(R + (size_t)row * kD))[tid];
    float s  = v.x + v.y + v.z + v.w;
    float ss = v.x * v.x + v.y * v.y + v.z * v.z + v.w * v.w;
#pragma unroll
    for (int off = 32; off > 0; off >>= 1) {
        s  += __shfl_down(s, off, 64);
        ss += __shfl_down(ss, off, 64);
    }
    __shared__ float ws_s[4], ws_ss[4];
    __shared__ float mu_sh, inv_sh;
    const int lane = tid & 63, w = tid >> 6;
    if (lane == 0) { ws_s[w] = s; ws_ss[w] = ss; }
    __syncthreads();
    if (tid == 0) {
        float S1 = ws_s[0] + ws_s[1] + ws_s[2] + ws_s[3];
        float S2 = ws_ss[0] + ws_ss[1] + ws_ss[2] + ws_ss[3];
        float mu = S1 * (1.0f / kD);
        float var = S2 * (1.0f / kD) - mu * mu;
        mu_sh = mu;
        inv_sh = rsqrtf(var + 1e-5f);
    }
    __syncthreads();
    const float mu = mu_sh, inv = inv_sh;
    const float4 g  = ((const float4*)gamma)[tid];
    const float4 bb = ((const float4*)beta)[tid];
    float4 o;
    o.x = (v.x - mu) * inv * g.x + bb.x;
    o.y = (v.y - mu) * inv * g.y + bb.y;
    o.z = (v.z - mu) * inv * g.z + bb.z;
    o.w = (v.w - mu) * inv * g.w + bb.w;
    ((float4*)(out + (size_t)row * kD))[tid] = o;
}

// ---------------------------------------------------------------------------
// Workspace layout (64 MB peak, aliasing is stream-ordered-safe):
//   [0,   8MB)  Xb bf16
//   [8,  16MB)  Wb bf16 wq|wk|wv|wo
//   [16, 40MB)  QKV bf16 Q|K|V  (Q pre-scaled by 0.125*log2e)
//   [40, 48MB)  Ctx bf16
//   [48, 64MB)  VT bf16 [32][64][2048]; ALIASES R (written strictly later)
// ---------------------------------------------------------------------------
extern "C" void kernel_launch(void* const* d_in, const int* in_sizes, int n_in,
                              void* d_out, int out_size, void* d_ws, size_t ws_size,
                              hipStream_t stream) {
    const float* x     = (const float*)d_in[0];
    const float* wq    = (const float*)d_in[1];
    const float* wk    = (const float*)d_in[2];
    const float* wv    = (const float*)d_in[3];
    const float* wo    = (const float*)d_in[4];
    const float* gamma = (const float*)d_in[5];
    const float* beta  = (const float*)d_in[6];
    float* out = (float*)d_out;

    char* ws = (char*)d_ws;
    unsigned short* Xb  = (unsigned short*)(ws);
    unsigned short* Wb  = (unsigned short*)(ws + (8u  << 20));
    unsigned short* QKV = (unsigned short*)(ws + (16u << 20));
    unsigned short* Qb  = QKV;
    unsigned short* Kb  = QKV + (size_t)kBS * kD;
    unsigned short* Vb  = QKV + (size_t)2 * kBS * kD;
    unsigned short* Ctx = (unsigned short*)(ws + (40u << 20));
    unsigned short* VT  = (unsigned short*)(ws + (48u << 20));
    float* R            = (float*)(ws + (48u << 20));  // aliases VT

    convert_kernel<<<8192, 256, 0, stream>>>(x, wq, wk, wv, wo, Xb, Wb);

    gemm_nt<0><<<dim3(kD / 128, kBS / 128, 3), 256, 0, stream>>>(
        Xb, Wb, QKV, nullptr, kBS, kD, kD);

    stats_vt_kernel<<<1024, 128, 0, stream>>>(Qb, Kb, Vb, VT);

    ctx_kernel<<<1024, 128, 0, stream>>>(Qb, Kb, VT, Ctx);

    gemm_nt<1><<<dim3(kD / 128, kBS / 128, 1), 256, 0, stream>>>(
        Ctx, Wb + (size_t)3 * kD * kD, R, x, kBS, kD, kD);

    ln_kernel<<<kBS, 256, 0, stream>>>(R, gamma, beta, out);
}

// Round 14
// 256.620 us; speedup vs baseline: 1.2328x; 1.0280x over previous
//
#include <hip/hip_runtime.h>
#include <hip/hip_bf16.h>

// Problem constants
constexpr int kB   = 2;
constexpr int kS   = 2048;
constexpr int kD   = 1024;
constexpr int kH   = 16;
constexpr int kDh  = 64;
constexpr int kBS  = kB * kS;          // 4096 rows

typedef __attribute__((ext_vector_type(8))) short short8;   // 8 bf16 = 4 VGPRs
typedef __attribute__((ext_vector_type(4))) float floatx4;  // MFMA acc

__device__ inline unsigned short f2b(float f) {
    __hip_bfloat16 h = __float2bfloat16(f);
    return *reinterpret_cast<unsigned short*>(&h);
}

__device__ inline float b2f(unsigned short u) {
    union { unsigned u; float f; } cv;
    cv.u = (unsigned)u << 16;
    return cv.f;
}

__device__ inline floatx4 mfma16(short8 a, short8 b, floatx4 c) {
    return __builtin_amdgcn_mfma_f32_16x16x32_bf16(a, b, c, 0, 0, 0);
}

// async global->LDS, 16B per lane; LDS dest = wave-uniform base + lane*16
__device__ inline void gload16(const unsigned short* g, unsigned short* l) {
    __builtin_amdgcn_global_load_lds(
        (const __attribute__((address_space(1))) void*)g,
        (__attribute__((address_space(3))) void*)l, 16, 0, 0);
}

// ---------------------------------------------------------------------------
// K0: fp32 -> bf16 conversion of x (4M elems) and the 4 weights (4 x 1M elems)
// ---------------------------------------------------------------------------
__global__ void convert_kernel(const float* __restrict__ x,
                               const float* __restrict__ wq, const float* __restrict__ wk,
                               const float* __restrict__ wv, const float* __restrict__ wo,
                               unsigned short* __restrict__ xb, unsigned short* __restrict__ wb) {
    int gid = blockIdx.x * blockDim.x + threadIdx.x;
    long i4 = (long)gid * 4;
    const float* src;
    unsigned short* dst;
    long off;
    if (i4 < (long)kBS * kD) {
        src = x; dst = xb; off = i4;
    } else {
        long w = i4 - (long)kBS * kD;
        int sel = (int)(w >> 20);
        off = w & 1048575;
        src = (sel == 0) ? wq : (sel == 1) ? wk : (sel == 2) ? wv : wo;
        dst = wb + (long)sel * 1048576;
    }
    float4 v = *(const float4*)(src + off);
    ushort4 o;
    o.x = f2b(v.x); o.y = f2b(v.y); o.z = f2b(v.z); o.w = f2b(v.w);
    *(ushort4*)(dst + off) = o;
}

// ---------------------------------------------------------------------------
// K1: NT GEMM  C[M,N] = A[M,K] @ B[N,K]^T   (bf16 in, fp32 accum)
// BK=64: 32 MFMAs per barrier-pair. Staging via global_load_lds w=16 with
// 8-chunk XOR swizzle; 32 KB LDS, 2 blocks/CU.
// MODE 0: bf16 C; z==0 (Q) scaled by 0.125*log2(e) (exp2 domain).
// MODE 1: fp32 C + residual.
// ---------------------------------------------------------------------------
template <int MODE>
__launch_bounds__(256, 2)
__global__ void gemm_nt(const unsigned short* __restrict__ A,
                        const unsigned short* __restrict__ Bw,
                        void* __restrict__ Cout,
                        const float* __restrict__ resid,
                        int M, int N, int K) {
    __shared__ __align__(16) unsigned short As[128 * 64];
    __shared__ __align__(16) unsigned short Bs[128 * 64];

    const int z  = blockIdx.z;
    const unsigned short* Bp = Bw + (size_t)z * N * K;
    const int m0 = blockIdx.y * 128, n0 = blockIdx.x * 128;
    const int tid  = threadIdx.x;
    const int lane = tid & 63, wv = tid >> 6;
    const int wm = wv >> 1, wn = wv & 1;
    const int quad = lane >> 4, l16 = lane & 15;

    floatx4 acc[4][4] = {};

    const int r0 = lane >> 3;
    const int jc = ((lane & 7) ^ r0) * 8;
    const unsigned short* Ag[4];
    const unsigned short* Bg[4];
    unsigned short* Asd[4];
    unsigned short* Bsd[4];
#pragma unroll
    for (int seg = 0; seg < 4; seg++) {
        const int row = seg * 32 + wv * 8 + r0;        // 0..127
        Ag[seg] = A  + (size_t)(m0 + row) * K + jc;    // + k0 per iter
        Bg[seg] = Bp + (size_t)(n0 + row) * K + jc;
        Asd[seg] = As + (seg * 32 + wv * 8) * 64;      // wave-uniform
        Bsd[seg] = Bs + (seg * 32 + wv * 8) * 64;
    }

    const int pk0 = (quad ^ (l16 & 7)) * 8;
    const int pk1 = ((4 + quad) ^ (l16 & 7)) * 8;

    for (int k0 = 0; k0 < K; k0 += 64) {
        __syncthreads();
#pragma unroll
        for (int seg = 0; seg < 4; seg++) {
            gload16(Ag[seg] + k0, Asd[seg]);
            gload16(Bg[seg] + k0, Bsd[seg]);
        }
        __syncthreads();

#pragma unroll
        for (int h = 0; h < 2; h++) {
            const int pk = h ? pk1 : pk0;
            short8 af[4], bf[4];
#pragma unroll
            for (int i = 0; i < 4; i++)
                af[i] = *(const short8*)(As + (wm * 64 + i * 16 + l16) * 64 + pk);
#pragma unroll
            for (int j = 0; j < 4; j++)
                bf[j] = *(const short8*)(Bs + (wn * 64 + j * 16 + l16) * 64 + pk);
#pragma unroll
            for (int i = 0; i < 4; i++)
#pragma unroll
                for (int j = 0; j < 4; j++)
                    acc[i][j] = mfma16(af[i], bf[j], acc[i][j]);
        }
    }

#pragma unroll
    for (int i = 0; i < 4; i++)
#pragma unroll
        for (int j = 0; j < 4; j++) {
            const int row = m0 + wm * 64 + i * 16 + quad * 4;
            const int col = n0 + wn * 64 + j * 16 + l16;
#pragma unroll
            for (int r = 0; r < 4; r++) {
                float v = acc[i][j][r];
                if (MODE == 0) {
                    if (z == 0) v *= 0.18033688f;   // 0.125 * log2(e)
                    ((unsigned short*)Cout)[(size_t)z * M * N + (size_t)(row + r) * N + col] = f2b(v);
                } else {
                    size_t idx = (size_t)(row + r) * N + col;
                    ((float*)Cout)[idx] = v + resid[idx];
                }
            }
        }
}

// ---------------------------------------------------------------------------
// K2: FUSED column-softmax denominators + scaled V^T production.
// Phase 1: invl[k] = 1/sum_q exp2(s[q,k]) for this block's 64 keys
//   (K-stationary, Q staged via global_load_lds, XCD-swizzled bh decode).
// Phase 2: VT[bh][d][k] = V[b][k][h*64+d] * invl[k], invl via LDS broadcast.
// ---------------------------------------------------------------------------
__launch_bounds__(128, 3)
__global__ void stats_vt_kernel(const unsigned short* __restrict__ Qb,
                                const unsigned short* __restrict__ Kb,
                                const unsigned short* __restrict__ Vb,
                                unsigned short* __restrict__ VT) {
    __shared__ __align__(16) unsigned short Qs[64 * 68];  // staging (64) / transpose tile (65)
    __shared__ float s_inv[64];

    const int id = blockIdx.x;                       // 0..1023
    const int bh = (id & 7) + 8 * ((id >> 3) & 3);   // XCD-grouped
    const int keyblk = id >> 5;                      // 0..31
    const int b = bh >> 4, h = bh & 15;
    const int tid = threadIdx.x, lane = tid & 63, w = tid >> 6;   // w = 0..1
    const int quad = lane >> 4, l16 = lane & 15;
    const int keybase = keyblk * 64 + w * 32;

    short8 ak[2][2];
#pragma unroll
    for (int s = 0; s < 2; s++) {
        const unsigned short* Krow = Kb + (size_t)(b * kS + keybase + s * 16 + l16) * kD + h * kDh;
        ak[s][0] = *(const short8*)(Krow + quad * 8);
        ak[s][1] = *(const short8*)(Krow + 32 + quad * 8);
    }

    const int r0 = lane >> 3;
    const int jc = ((lane & 7) ^ r0) * 8;
    const unsigned short* Qg[4];
    unsigned short* Ql[4];
#pragma unroll
    for (int seg = 0; seg < 4; seg++) {
        const int row = seg * 16 + w * 8 + r0;              // 0..63
        Qg[seg] = Qb + (size_t)(b * kS + row) * kD + h * kDh + jc;   // + q0*kD per chunk
        Ql[seg] = Qs + (seg * 16 + w * 8) * 64;             // wave-uniform
    }

    const int pk0 = (quad ^ (l16 & 7)) * 8;
    const int pk1 = ((4 + quad) ^ (l16 & 7)) * 8;

    float lacc[2][4] = {};

    for (int q0 = 0; q0 < kS; q0 += 64) {
        __syncthreads();
#pragma unroll
        for (int seg = 0; seg < 4; seg++)
            gload16(Qg[seg] + (size_t)q0 * kD, Ql[seg]);
        __syncthreads();

#pragma unroll
        for (int c = 0; c < 4; c++) {
            const unsigned short* row = Qs + (c * 16 + l16) * 64;
            short8 bq0 = *(const short8*)(row + pk0);
            short8 bq1 = *(const short8*)(row + pk1);
#pragma unroll
            for (int s = 0; s < 2; s++) {
                floatx4 t = {0.f, 0.f, 0.f, 0.f};
                t = mfma16(ak[s][0], bq0, t);
                t = mfma16(ak[s][1], bq1, t);
#pragma unroll
                for (int r = 0; r < 4; r++)
                    lacc[s][r] += exp2f(t[r]);
            }
        }
    }

#pragma unroll
    for (int off = 1; off <= 8; off <<= 1)
#pragma unroll
        for (int s = 0; s < 2; s++)
#pragma unroll
            for (int r = 0; r < 4; r++)
                lacc[s][r] += __shfl_xor(lacc[s][r], off, 64);

    __syncthreads();   // Qs reads done before tile reuse; also orders s_inv
    if (l16 == 0) {
#pragma unroll
        for (int s = 0; s < 2; s++)
#pragma unroll
            for (int r = 0; r < 4; r++)
                s_inv[w * 32 + s * 16 + quad * 4 + r] = 1.0f / lacc[s][r];
    }
    __syncthreads();

    unsigned short* tile = Qs;   // reuse, stride 65
    {
        const int kr = tid >> 1, dc = (tid & 1) * 32;
        const float iv = s_inv[kr];
        const unsigned short* src = Vb + (size_t)(b * kS + keyblk * 64 + kr) * kD + h * kDh + dc;
        unsigned short vs[32];
        *(uint4*)(vs)      = *(const uint4*)(src);
        *(uint4*)(vs + 8)  = *(const uint4*)(src + 8);
        *(uint4*)(vs + 16) = *(const uint4*)(src + 16);
        *(uint4*)(vs + 24) = *(const uint4*)(src + 24);
#pragma unroll
        for (int i = 0; i < 32; i++)
            tile[kr * 65 + dc + i] = f2b(b2f(vs[i]) * iv);
    }
    __syncthreads();
    {
        const int d = tid >> 1, kc = (tid & 1) * 32;
        unsigned short os[32];
#pragma unroll
        for (int j = 0; j < 32; j++) os[j] = tile[(kc + j) * 65 + d];
        unsigned short* dst = VT + (size_t)bh * kDh * kS + (size_t)d * kS + keyblk * 64 + kc;
        *(uint4*)(dst)      = *(uint4*)(os);
        *(uint4*)(dst + 8)  = *(uint4*)(os + 8);
        *(uint4*)(dst + 16) = *(uint4*)(os + 16);
        *(uint4*)(dst + 24) = *(uint4*)(os + 24);
    }
}

// ---------------------------------------------------------------------------
// K3: ctx = exp2(S) @ VT^T — round 14: 4 waves share one K/VT staging.
// Block = 256 threads (4 waves x 32 q = 128 q); grid 512, XCD-swizzled.
// Staging DMA per CU halves (1 tile serves 4 waves); occupancy rises to
// 4 blocks x 4 waves = 16 waves/CU. Inner code = round-12 best (S^T operand
// swap -> packed b64 P writes, b128 P reads, truncating bf16).
// ---------------------------------------------------------------------------
__launch_bounds__(256, 4)
__global__ void ctx_kernel(const unsigned short* __restrict__ Qb,
                           const unsigned short* __restrict__ Kb,
                           const unsigned short* __restrict__ VT,
                           unsigned short* __restrict__ Ctx) {
    constexpr int LDP = 72;
    __shared__ __align__(16) unsigned short Ks[64 * 64];
    __shared__ __align__(16) unsigned short VTs[64 * 64];
    __shared__ __align__(16) unsigned short Pt[4][32 * LDP];

    const int id = blockIdx.x;                       // 0..511
    const int bh = (id & 7) + 8 * ((id >> 3) & 3);   // XCD-grouped
    const int qblk = id >> 5;                        // 0..15
    const int b = bh >> 4, h = bh & 15;
    const int tid = threadIdx.x, lane = tid & 63, w = tid >> 6;   // w = 0..3
    const int quad = lane >> 4, l16 = lane & 15;
    const int qbase = qblk * 128 + w * 32;

    short8 aq[2][2];
#pragma unroll
    for (int s = 0; s < 2; s++) {
        const unsigned short* Qrow = Qb + (size_t)(b * kS + qbase + s * 16 + l16) * kD + h * kDh;
        aq[s][0] = *(const short8*)(Qrow + quad * 8);
        aq[s][1] = *(const short8*)(Qrow + 32 + quad * 8);
    }
    floatx4 acc[2][4] = {};

    const unsigned short* Kbase = Kb + (size_t)(b * kS) * kD + h * kDh;
    const unsigned short* VTb   = VT + (size_t)bh * kDh * kS;

    // staging: wave w covers rows w*16 .. w*16+15 (2 segs of 8 rows)
    const int r0 = lane >> 3;
    const int jc = ((lane & 7) ^ r0) * 8;
    const unsigned short* Kg[2];
    const unsigned short* Vg[2];
    unsigned short* Kl[2];
    unsigned short* Vl[2];
#pragma unroll
    for (int seg = 0; seg < 2; seg++) {
        const int row = w * 16 + seg * 8 + r0;         // 0..63
        Kg[seg] = Kbase + (size_t)row * kD + jc;       // + k0*kD per chunk
        Vg[seg] = VTb + (size_t)row * kS + jc;         // + k0 per chunk
        Kl[seg] = Ks  + (w * 16 + seg * 8) * 64;       // wave-uniform
        Vl[seg] = VTs + (w * 16 + seg * 8) * 64;
    }

    unsigned short* P = Pt[w];
    // P[q][k] stride LDP; physical 16-block kp = (k>>4) ^ (q&3).
    unsigned short* pw[4];
#pragma unroll
    for (int c = 0; c < 4; c++)
        pw[c] = P + l16 * LDP + ((c ^ (l16 & 3)) * 16) + quad * 4;
    const unsigned short* pr[2];
#pragma unroll
    for (int h2 = 0; h2 < 2; h2++)
        pr[h2] = P + l16 * LDP + (((h2 * 2 + (quad >> 1)) ^ (l16 & 3)) * 16) + (quad & 1) * 8;

    const int pk0 = (quad ^ (l16 & 7)) * 8;
    const int pk1 = ((4 + quad) ^ (l16 & 7)) * 8;

    for (int k0 = 0; k0 < kS; k0 += 64) {
        __syncthreads();
#pragma unroll
        for (int seg = 0; seg < 2; seg++) {
            gload16(Kg[seg] + (size_t)k0 * kD, Kl[seg]);
            gload16(Vg[seg] + k0, Vl[seg]);
        }
        __syncthreads();

        short8 bk[4][2];
#pragma unroll
        for (int c = 0; c < 4; c++) {
            const unsigned short* row = Ks + (c * 16 + l16) * 64;
            bk[c][0] = *(const short8*)(row + pk0);
            bk[c][1] = *(const short8*)(row + pk1);
        }
        // S^T tiles: mfma(A=K-frag, B=Q-frag) -> D[key][q]
        floatx4 sc[2][4];
#pragma unroll
        for (int s = 0; s < 2; s++)
#pragma unroll
            for (int c = 0; c < 4; c++) {
                floatx4 t = {0.f, 0.f, 0.f, 0.f};
                t = mfma16(bk[c][0], aq[s][0], t);
                sc[s][c] = mfma16(bk[c][1], aq[s][1], t);
            }
        // exp2 -> packed truncating bf16 -> one b64 per (s,c)
#pragma unroll
        for (int s = 0; s < 2; s++)
#pragma unroll
            for (int c = 0; c < 4; c++) {
                union { float f; unsigned u; } e0, e1, e2, e3;
                e0.f = exp2f(sc[s][c][0]);
                e1.f = exp2f(sc[s][c][1]);
                e2.f = exp2f(sc[s][c][2]);
                e3.f = exp2f(sc[s][c][3]);
                uint2 pk;
                pk.x = (e0.u >> 16) | (e1.u & 0xffff0000u);
                pk.y = (e2.u >> 16) | (e3.u & 0xffff0000u);
                *(uint2*)(pw[c] + s * 16 * LDP) = pk;
            }

        short8 bv[4][2];
#pragma unroll
        for (int t = 0; t < 4; t++) {
            const unsigned short* row = VTs + (t * 16 + l16) * 64;
            bv[t][0] = *(const short8*)(row + pk0);
            bv[t][1] = *(const short8*)(row + pk1);
        }
#pragma unroll
        for (int s = 0; s < 2; s++) {
            short8 ap0 = *(const short8*)(pr[0] + s * 16 * LDP);
            short8 ap1 = *(const short8*)(pr[1] + s * 16 * LDP);
#pragma unroll
            for (int t = 0; t < 4; t++) {
                acc[s][t] = mfma16(ap0, bv[t][0], acc[s][t]);
                acc[s][t] = mfma16(ap1, bv[t][1], acc[s][t]);
            }
        }
    }

#pragma unroll
    for (int s = 0; s < 2; s++)
#pragma unroll
        for (int t = 0; t < 4; t++)
#pragma unroll
            for (int r = 0; r < 4; r++)
                Ctx[(size_t)(b * kS + qbase + s * 16 + quad * 4 + r) * kD + h * kDh + t * 16 + l16] =
                    f2b(acc[s][t][r]);
}

// ---------------------------------------------------------------------------
// K4: row LayerNorm
// ---------------------------------------------------------------------------
__global__ void ln_kernel(const float* __restrict__ R, const float* __restrict__ gamma,
                          const float* __restrict__ beta, float* __restrict__ out) {
    const int row = blockIdx.x;
    const int tid = threadIdx.x;
    const float4 v = ((const float4*)(R + (size_t)row * kD))[tid];
    float s  = v.x + v.y + v.z + v.w;
    float ss = v.x * v.x + v.y * v.y + v.z * v.z + v.w * v.w;
#pragma unroll
    for (int off = 32; off > 0; off >>= 1) {
        s  += __shfl_down(s, off, 64);
        ss += __shfl_down(ss, off, 64);
    }
    __shared__ float ws_s[4], ws_ss[4];
    __shared__ float mu_sh, inv_sh;
    const int lane = tid & 63, w = tid >> 6;
    if (lane == 0) { ws_s[w] = s; ws_ss[w] = ss; }
    __syncthreads();
    if (tid == 0) {
        float S1 = ws_s[0] + ws_s[1] + ws_s[2] + ws_s[3];
        float S2 = ws_ss[0] + ws_ss[1] + ws_ss[2] + ws_ss[3];
        float mu = S1 * (1.0f / kD);
        float var = S2 * (1.0f / kD) - mu * mu;
        mu_sh = mu;
        inv_sh = rsqrtf(var + 1e-5f);
    }
    __syncthreads();
    const float mu = mu_sh, inv = inv_sh;
    const float4 g  = ((const float4*)gamma)[tid];
    const float4 bb = ((const float4*)beta)[tid];
    float4 o;
    o.x = (v.x - mu) * inv * g.x + bb.x;
    o.y = (v.y - mu) * inv * g.y + bb.y;
    o.z = (v.z - mu) * inv * g.z + bb.z;
    o.w = (v.w - mu) * inv * g.w + bb.w;
    ((float4*)(out + (size_t)row * kD))[tid] = o;
}

// ---------------------------------------------------------------------------
// Workspace layout (64 MB peak, aliasing is stream-ordered-safe):
//   [0,   8MB)  Xb bf16
//   [8,  16MB)  Wb bf16 wq|wk|wv|wo
//   [16, 40MB)  QKV bf16 Q|K|V  (Q pre-scaled by 0.125*log2e)
//   [40, 48MB)  Ctx bf16
//   [48, 64MB)  VT bf16 [32][64][2048]; ALIASES R (written strictly later)
// ---------------------------------------------------------------------------
extern "C" void kernel_launch(void* const* d_in, const int* in_sizes, int n_in,
                              void* d_out, int out_size, void* d_ws, size_t ws_size,
                              hipStream_t stream) {
    const float* x     = (const float*)d_in[0];
    const float* wq    = (const float*)d_in[1];
    const float* wk    = (const float*)d_in[2];
    const float* wv    = (const float*)d_in[3];
    const float* wo    = (const float*)d_in[4];
    const float* gamma = (const float*)d_in[5];
    const float* beta  = (const float*)d_in[6];
    float* out = (float*)d_out;

    char* ws = (char*)d_ws;
    unsigned short* Xb  = (unsigned short*)(ws);
    unsigned short* Wb  = (unsigned short*)(ws + (8u  << 20));
    unsigned short* QKV = (unsigned short*)(ws + (16u << 20));
    unsigned short* Qb  = QKV;
    unsigned short* Kb  = QKV + (size_t)kBS * kD;
    unsigned short* Vb  = QKV + (size_t)2 * kBS * kD;
    unsigned short* Ctx = (unsigned short*)(ws + (40u << 20));
    unsigned short* VT  = (unsigned short*)(ws + (48u << 20));
    float* R            = (float*)(ws + (48u << 20));  // aliases VT

    convert_kernel<<<8192, 256, 0, stream>>>(x, wq, wk, wv, wo, Xb, Wb);

    gemm_nt<0><<<dim3(kD / 128, kBS / 128, 3), 256, 0, stream>>>(
        Xb, Wb, QKV, nullptr, kBS, kD, kD);

    stats_vt_kernel<<<1024, 128, 0, stream>>>(Qb, Kb, Vb, VT);

    ctx_kernel<<<512, 256, 0, stream>>>(Qb, Kb, VT, Ctx);

    gemm_nt<1><<<dim3(kD / 128, kBS / 128, 1), 256, 0, stream>>>(
        Ctx, Wb + (size_t)3 * kD * kD, R, x, kBS, kD, kD);

    ln_kernel<<<kBS, 256, 0, stream>>>(R, gamma, beta, out);
}

// Round 15
// 248.508 us; speedup vs baseline: 1.2730x; 1.0326x over previous
//
#include <hip/hip_runtime.h>
#include <hip/hip_bf16.h>

// Problem constants
constexpr int kB   = 2;
constexpr int kS   = 2048;
constexpr int kD   = 1024;
constexpr int kH   = 16;
constexpr int kDh  = 64;
constexpr int kBS  = kB * kS;          // 4096 rows

typedef __attribute__((ext_vector_type(8))) short short8;   // 8 bf16 = 4 VGPRs
typedef __attribute__((ext_vector_type(4))) float floatx4;  // MFMA acc

__device__ inline unsigned short f2b(float f) {
    __hip_bfloat16 h = __float2bfloat16(f);
    return *reinterpret_cast<unsigned short*>(&h);
}

__device__ inline float b2f(unsigned short u) {
    union { unsigned u; float f; } cv;
    cv.u = (unsigned)u << 16;
    return cv.f;
}

__device__ inline floatx4 mfma16(short8 a, short8 b, floatx4 c) {
    return __builtin_amdgcn_mfma_f32_16x16x32_bf16(a, b, c, 0, 0, 0);
}

// async global->LDS, 16B per lane; LDS dest = wave-uniform base + lane*16
__device__ inline void gload16(const unsigned short* g, unsigned short* l) {
    __builtin_amdgcn_global_load_lds(
        (const __attribute__((address_space(1))) void*)g,
        (__attribute__((address_space(3))) void*)l, 16, 0, 0);
}

// ---------------------------------------------------------------------------
// K0: fp32 -> bf16 conversion of x (4M elems) and the 4 weights (4 x 1M elems)
// ---------------------------------------------------------------------------
__global__ void convert_kernel(const float* __restrict__ x,
                               const float* __restrict__ wq, const float* __restrict__ wk,
                               const float* __restrict__ wv, const float* __restrict__ wo,
                               unsigned short* __restrict__ xb, unsigned short* __restrict__ wb) {
    int gid = blockIdx.x * blockDim.x + threadIdx.x;
    long i4 = (long)gid * 4;
    const float* src;
    unsigned short* dst;
    long off;
    if (i4 < (long)kBS * kD) {
        src = x; dst = xb; off = i4;
    } else {
        long w = i4 - (long)kBS * kD;
        int sel = (int)(w >> 20);
        off = w & 1048575;
        src = (sel == 0) ? wq : (sel == 1) ? wk : (sel == 2) ? wv : wo;
        dst = wb + (long)sel * 1048576;
    }
    float4 v = *(const float4*)(src + off);
    ushort4 o;
    o.x = f2b(v.x); o.y = f2b(v.y); o.z = f2b(v.z); o.w = f2b(v.w);
    *(ushort4*)(dst + off) = o;
}

// ---------------------------------------------------------------------------
// K1: NT GEMM  C[M,N] = A[M,K] @ B[N,K]^T   (bf16 in, fp32 accum)
// BK=64: 32 MFMAs per barrier-pair. Staging via global_load_lds w=16 with
// 8-chunk XOR swizzle; 32 KB LDS, 2 blocks/CU.
// MODE 0: bf16 C; z==0 (Q) scaled by 0.125*log2(e) (exp2 domain).
// MODE 1: fp32 C + residual.
// ---------------------------------------------------------------------------
template <int MODE>
__launch_bounds__(256, 2)
__global__ void gemm_nt(const unsigned short* __restrict__ A,
                        const unsigned short* __restrict__ Bw,
                        void* __restrict__ Cout,
                        const float* __restrict__ resid,
                        int M, int N, int K) {
    __shared__ __align__(16) unsigned short As[128 * 64];
    __shared__ __align__(16) unsigned short Bs[128 * 64];

    const int z  = blockIdx.z;
    const unsigned short* Bp = Bw + (size_t)z * N * K;
    const int m0 = blockIdx.y * 128, n0 = blockIdx.x * 128;
    const int tid  = threadIdx.x;
    const int lane = tid & 63, wv = tid >> 6;
    const int wm = wv >> 1, wn = wv & 1;
    const int quad = lane >> 4, l16 = lane & 15;

    floatx4 acc[4][4] = {};

    const int r0 = lane >> 3;
    const int jc = ((lane & 7) ^ r0) * 8;
    const unsigned short* Ag[4];
    const unsigned short* Bg[4];
    unsigned short* Asd[4];
    unsigned short* Bsd[4];
#pragma unroll
    for (int seg = 0; seg < 4; seg++) {
        const int row = seg * 32 + wv * 8 + r0;        // 0..127
        Ag[seg] = A  + (size_t)(m0 + row) * K + jc;    // + k0 per iter
        Bg[seg] = Bp + (size_t)(n0 + row) * K + jc;
        Asd[seg] = As + (seg * 32 + wv * 8) * 64;      // wave-uniform
        Bsd[seg] = Bs + (seg * 32 + wv * 8) * 64;
    }

    const int pk0 = (quad ^ (l16 & 7)) * 8;
    const int pk1 = ((4 + quad) ^ (l16 & 7)) * 8;

    for (int k0 = 0; k0 < K; k0 += 64) {
        __syncthreads();
#pragma unroll
        for (int seg = 0; seg < 4; seg++) {
            gload16(Ag[seg] + k0, Asd[seg]);
            gload16(Bg[seg] + k0, Bsd[seg]);
        }
        __syncthreads();

#pragma unroll
        for (int h = 0; h < 2; h++) {
            const int pk = h ? pk1 : pk0;
            short8 af[4], bf[4];
#pragma unroll
            for (int i = 0; i < 4; i++)
                af[i] = *(const short8*)(As + (wm * 64 + i * 16 + l16) * 64 + pk);
#pragma unroll
            for (int j = 0; j < 4; j++)
                bf[j] = *(const short8*)(Bs + (wn * 64 + j * 16 + l16) * 64 + pk);
#pragma unroll
            for (int i = 0; i < 4; i++)
#pragma unroll
                for (int j = 0; j < 4; j++)
                    acc[i][j] = mfma16(af[i], bf[j], acc[i][j]);
        }
    }

#pragma unroll
    for (int i = 0; i < 4; i++)
#pragma unroll
        for (int j = 0; j < 4; j++) {
            const int row = m0 + wm * 64 + i * 16 + quad * 4;
            const int col = n0 + wn * 64 + j * 16 + l16;
#pragma unroll
            for (int r = 0; r < 4; r++) {
                float v = acc[i][j][r];
                if (MODE == 0) {
                    if (z == 0) v *= 0.18033688f;   // 0.125 * log2(e)
                    ((unsigned short*)Cout)[(size_t)z * M * N + (size_t)(row + r) * N + col] = f2b(v);
                } else {
                    size_t idx = (size_t)(row + r) * N + col;
                    ((float*)Cout)[idx] = v + resid[idx];
                }
            }
        }
}

// ---------------------------------------------------------------------------
// K2: FUSED column-softmax denominators + scaled V^T — round 15: 4 waves
// share one Q staging tile. Block = 256 threads (4 waves x 32 keys = 128
// keys); grid 512, XCD-swizzled. Staging DMA per CU halves vs round 14.
// Phase 1: invl[k] = 1/sum_q exp2(s[q,k]) (K-stationary).
// Phase 2: VT[bh][d][k] = V[b][k][h*64+d] * invl[k], two 64-key groups.
// ---------------------------------------------------------------------------
__launch_bounds__(256, 4)
__global__ void stats_vt_kernel(const unsigned short* __restrict__ Qb,
                                const unsigned short* __restrict__ Kb,
                                const unsigned short* __restrict__ Vb,
                                unsigned short* __restrict__ VT) {
    __shared__ __align__(16) unsigned short Qs[64 * 68];  // staging (64) / transpose tile (65)
    __shared__ float s_inv[128];

    const int id = blockIdx.x;                       // 0..511
    const int bh = (id & 7) + 8 * ((id >> 3) & 3);   // XCD-grouped
    const int keyblk = id >> 5;                      // 0..15
    const int b = bh >> 4, h = bh & 15;
    const int tid = threadIdx.x, lane = tid & 63, w = tid >> 6;   // w = 0..3
    const int quad = lane >> 4, l16 = lane & 15;
    const int keybase = keyblk * 128 + w * 32;

    // A-frags: K rows (2 key-tiles x 2 dh-halves), held in regs
    short8 ak[2][2];
#pragma unroll
    for (int s = 0; s < 2; s++) {
        const unsigned short* Krow = Kb + (size_t)(b * kS + keybase + s * 16 + l16) * kD + h * kDh;
        ak[s][0] = *(const short8*)(Krow + quad * 8);
        ak[s][1] = *(const short8*)(Krow + 32 + quad * 8);
    }

    // staging: wave w covers rows w*16 .. w*16+15 (2 segs of 8 rows);
    // lane covers row seg*8 + (lane>>3), logical 16B chunk (lane&7)^r0
    const int r0 = lane >> 3;
    const int jc = ((lane & 7) ^ r0) * 8;
    const unsigned short* Qg[2];
    unsigned short* Ql[2];
#pragma unroll
    for (int seg = 0; seg < 2; seg++) {
        const int row = w * 16 + seg * 8 + r0;              // 0..63
        Qg[seg] = Qb + (size_t)(b * kS + row) * kD + h * kDh + jc;   // + q0*kD per chunk
        Ql[seg] = Qs + (w * 16 + seg * 8) * 64;             // wave-uniform
    }

    const int pk0 = (quad ^ (l16 & 7)) * 8;
    const int pk1 = ((4 + quad) ^ (l16 & 7)) * 8;

    float lacc[2][4] = {};

    for (int q0 = 0; q0 < kS; q0 += 64) {
        __syncthreads();
#pragma unroll
        for (int seg = 0; seg < 2; seg++)
            gload16(Qg[seg] + (size_t)q0 * kD, Ql[seg]);
        __syncthreads();

#pragma unroll
        for (int c = 0; c < 4; c++) {
            const unsigned short* row = Qs + (c * 16 + l16) * 64;
            short8 bq0 = *(const short8*)(row + pk0);
            short8 bq1 = *(const short8*)(row + pk1);
#pragma unroll
            for (int s = 0; s < 2; s++) {
                floatx4 t = {0.f, 0.f, 0.f, 0.f};
                t = mfma16(ak[s][0], bq0, t);
                t = mfma16(ak[s][1], bq1, t);
#pragma unroll
                for (int r = 0; r < 4; r++)
                    lacc[s][r] += exp2f(t[r]);
            }
        }
    }

    // reduce across the 16 l16 lanes within each quad
#pragma unroll
    for (int off = 1; off <= 8; off <<= 1)
#pragma unroll
        for (int s = 0; s < 2; s++)
#pragma unroll
            for (int r = 0; r < 4; r++)
                lacc[s][r] += __shfl_xor(lacc[s][r], off, 64);

    __syncthreads();   // Qs reads done before tile reuse; also orders s_inv
    if (l16 == 0) {
#pragma unroll
        for (int s = 0; s < 2; s++)
#pragma unroll
            for (int r = 0; r < 4; r++)
                s_inv[w * 32 + s * 16 + quad * 4 + r] = 1.0f / lacc[s][r];
    }
    __syncthreads();

    // Phase 2: scaled V^T for this block's 128 keys, two 64-key groups.
    unsigned short* tile = Qs;   // reuse, stride 65
#pragma unroll
    for (int g = 0; g < 2; g++) {
        const int kr = tid >> 2, dc = (tid & 3) * 16;
        {
            const float iv = s_inv[g * 64 + kr];
            const unsigned short* src =
                Vb + (size_t)(b * kS + keyblk * 128 + g * 64 + kr) * kD + h * kDh + dc;
            unsigned short vs[16];
            *(uint4*)(vs)     = *(const uint4*)(src);
            *(uint4*)(vs + 8) = *(const uint4*)(src + 8);
#pragma unroll
            for (int i = 0; i < 16; i++)
                tile[kr * 65 + dc + i] = f2b(b2f(vs[i]) * iv);
        }
        __syncthreads();
        {
            const int d = tid >> 2, kc = (tid & 3) * 16;
            unsigned short os[16];
#pragma unroll
            for (int j = 0; j < 16; j++) os[j] = tile[(kc + j) * 65 + d];
            unsigned short* dst =
                VT + (size_t)bh * kDh * kS + (size_t)d * kS + keyblk * 128 + g * 64 + kc;
            *(uint4*)(dst)     = *(uint4*)(os);
            *(uint4*)(dst + 8) = *(uint4*)(os + 8);
        }
        __syncthreads();   // tile reuse for next group
    }
}

// ---------------------------------------------------------------------------
// K3: ctx = exp2(S) @ VT^T — round-14 best: 4 waves share one K/VT staging.
// Block = 256 threads (4 waves x 32 q = 128 q); grid 512, XCD-swizzled.
// Inner code = round-12 (S^T operand swap -> packed b64 P writes, b128 P
// reads, truncating bf16). STRUCTURALLY FROZEN (rounds 8-14 explored).
// ---------------------------------------------------------------------------
__launch_bounds__(256, 4)
__global__ void ctx_kernel(const unsigned short* __restrict__ Qb,
                           const unsigned short* __restrict__ Kb,
                           const unsigned short* __restrict__ VT,
                           unsigned short* __restrict__ Ctx) {
    constexpr int LDP = 72;
    __shared__ __align__(16) unsigned short Ks[64 * 64];
    __shared__ __align__(16) unsigned short VTs[64 * 64];
    __shared__ __align__(16) unsigned short Pt[4][32 * LDP];

    const int id = blockIdx.x;                       // 0..511
    const int bh = (id & 7) + 8 * ((id >> 3) & 3);   // XCD-grouped
    const int qblk = id >> 5;                        // 0..15
    const int b = bh >> 4, h = bh & 15;
    const int tid = threadIdx.x, lane = tid & 63, w = tid >> 6;   // w = 0..3
    const int quad = lane >> 4, l16 = lane & 15;
    const int qbase = qblk * 128 + w * 32;

    short8 aq[2][2];
#pragma unroll
    for (int s = 0; s < 2; s++) {
        const unsigned short* Qrow = Qb + (size_t)(b * kS + qbase + s * 16 + l16) * kD + h * kDh;
        aq[s][0] = *(const short8*)(Qrow + quad * 8);
        aq[s][1] = *(const short8*)(Qrow + 32 + quad * 8);
    }
    floatx4 acc[2][4] = {};

    const unsigned short* Kbase = Kb + (size_t)(b * kS) * kD + h * kDh;
    const unsigned short* VTb   = VT + (size_t)bh * kDh * kS;

    const int r0 = lane >> 3;
    const int jc = ((lane & 7) ^ r0) * 8;
    const unsigned short* Kg[2];
    const unsigned short* Vg[2];
    unsigned short* Kl[2];
    unsigned short* Vl[2];
#pragma unroll
    for (int seg = 0; seg < 2; seg++) {
        const int row = w * 16 + seg * 8 + r0;         // 0..63
        Kg[seg] = Kbase + (size_t)row * kD + jc;       // + k0*kD per chunk
        Vg[seg] = VTb + (size_t)row * kS + jc;         // + k0 per chunk
        Kl[seg] = Ks  + (w * 16 + seg * 8) * 64;       // wave-uniform
        Vl[seg] = VTs + (w * 16 + seg * 8) * 64;
    }

    unsigned short* P = Pt[w];
    unsigned short* pw[4];
#pragma unroll
    for (int c = 0; c < 4; c++)
        pw[c] = P + l16 * LDP + ((c ^ (l16 & 3)) * 16) + quad * 4;
    const unsigned short* pr[2];
#pragma unroll
    for (int h2 = 0; h2 < 2; h2++)
        pr[h2] = P + l16 * LDP + (((h2 * 2 + (quad >> 1)) ^ (l16 & 3)) * 16) + (quad & 1) * 8;

    const int pk0 = (quad ^ (l16 & 7)) * 8;
    const int pk1 = ((4 + quad) ^ (l16 & 7)) * 8;

    for (int k0 = 0; k0 < kS; k0 += 64) {
        __syncthreads();
#pragma unroll
        for (int seg = 0; seg < 2; seg++) {
            gload16(Kg[seg] + (size_t)k0 * kD, Kl[seg]);
            gload16(Vg[seg] + k0, Vl[seg]);
        }
        __syncthreads();

        short8 bk[4][2];
#pragma unroll
        for (int c = 0; c < 4; c++) {
            const unsigned short* row = Ks + (c * 16 + l16) * 64;
            bk[c][0] = *(const short8*)(row + pk0);
            bk[c][1] = *(const short8*)(row + pk1);
        }
        // S^T tiles: mfma(A=K-frag, B=Q-frag) -> D[key][q]
        floatx4 sc[2][4];
#pragma unroll
        for (int s = 0; s < 2; s++)
#pragma unroll
            for (int c = 0; c < 4; c++) {
                floatx4 t = {0.f, 0.f, 0.f, 0.f};
                t = mfma16(bk[c][0], aq[s][0], t);
                sc[s][c] = mfma16(bk[c][1], aq[s][1], t);
            }
        // exp2 -> packed truncating bf16 -> one b64 per (s,c)
#pragma unroll
        for (int s = 0; s < 2; s++)
#pragma unroll
            for (int c = 0; c < 4; c++) {
                union { float f; unsigned u; } e0, e1, e2, e3;
                e0.f = exp2f(sc[s][c][0]);
                e1.f = exp2f(sc[s][c][1]);
                e2.f = exp2f(sc[s][c][2]);
                e3.f = exp2f(sc[s][c][3]);
                uint2 pk;
                pk.x = (e0.u >> 16) | (e1.u & 0xffff0000u);
                pk.y = (e2.u >> 16) | (e3.u & 0xffff0000u);
                *(uint2*)(pw[c] + s * 16 * LDP) = pk;
            }

        short8 bv[4][2];
#pragma unroll
        for (int t = 0; t < 4; t++) {
            const unsigned short* row = VTs + (t * 16 + l16) * 64;
            bv[t][0] = *(const short8*)(row + pk0);
            bv[t][1] = *(const short8*)(row + pk1);
        }
#pragma unroll
        for (int s = 0; s < 2; s++) {
            short8 ap0 = *(const short8*)(pr[0] + s * 16 * LDP);
            short8 ap1 = *(const short8*)(pr[1] + s * 16 * LDP);
#pragma unroll
            for (int t = 0; t < 4; t++) {
                acc[s][t] = mfma16(ap0, bv[t][0], acc[s][t]);
                acc[s][t] = mfma16(ap1, bv[t][1], acc[s][t]);
            }
        }
    }

#pragma unroll
    for (int s = 0; s < 2; s++)
#pragma unroll
        for (int t = 0; t < 4; t++)
#pragma unroll
            for (int r = 0; r < 4; r++)
                Ctx[(size_t)(b * kS + qbase + s * 16 + quad * 4 + r) * kD + h * kDh + t * 16 + l16] =
                    f2b(acc[s][t][r]);
}

// ---------------------------------------------------------------------------
// K4: row LayerNorm
// ---------------------------------------------------------------------------
__global__ void ln_kernel(const float* __restrict__ R, const float* __restrict__ gamma,
                          const float* __restrict__ beta, float* __restrict__ out) {
    const int row = blockIdx.x;
    const int tid = threadIdx.x;
    const float4 v = ((const float4*)(R + (size_t)row * kD))[tid];
    float s  = v.x + v.y + v.z + v.w;
    float ss = v.x * v.x + v.y * v.y + v.z * v.z + v.w * v.w;
#pragma unroll
    for (int off = 32; off > 0; off >>= 1) {
        s  += __shfl_down(s, off, 64);
        ss += __shfl_down(ss, off, 64);
    }
    __shared__ float ws_s[4], ws_ss[4];
    __shared__ float mu_sh, inv_sh;
    const int lane = tid & 63, w = tid >> 6;
    if (lane == 0) { ws_s[w] = s; ws_ss[w] = ss; }
    __syncthreads();
    if (tid == 0) {
        float S1 = ws_s[0] + ws_s[1] + ws_s[2] + ws_s[3];
        float S2 = ws_ss[0] + ws_ss[1] + ws_ss[2] + ws_ss[3];
        float mu = S1 * (1.0f / kD);
        float var = S2 * (1.0f / kD) - mu * mu;
        mu_sh = mu;
        inv_sh = rsqrtf(var + 1e-5f);
    }
    __syncthreads();
    const float mu = mu_sh, inv = inv_sh;
    const float4 g  = ((const float4*)gamma)[tid];
    const float4 bb = ((const float4*)beta)[tid];
    float4 o;
    o.x = (v.x - mu) * inv * g.x + bb.x;
    o.y = (v.y - mu) * inv * g.y + bb.y;
    o.z = (v.z - mu) * inv * g.z + bb.z;
    o.w = (v.w - mu) * inv * g.w + bb.w;
    ((float4*)(out + (size_t)row * kD))[tid] = o;
}

// ---------------------------------------------------------------------------
// Workspace layout (64 MB peak, aliasing is stream-ordered-safe):
//   [0,   8MB)  Xb bf16
//   [8,  16MB)  Wb bf16 wq|wk|wv|wo
//   [16, 40MB)  QKV bf16 Q|K|V  (Q pre-scaled by 0.125*log2e)
//   [40, 48MB)  Ctx bf16
//   [48, 64MB)  VT bf16 [32][64][2048]; ALIASES R (written strictly later)
// ---------------------------------------------------------------------------
extern "C" void kernel_launch(void* const* d_in, const int* in_sizes, int n_in,
                              void* d_out, int out_size, void* d_ws, size_t ws_size,
                              hipStream_t stream) {
    const float* x     = (const float*)d_in[0];
    const float* wq    = (const float*)d_in[1];
    const float* wk    = (const float*)d_in[2];
    const float* wv    = (const float*)d_in[3];
    const float* wo    = (const float*)d_in[4];
    const float* gamma = (const float*)d_in[5];
    const float* beta  = (const float*)d_in[6];
    float* out = (float*)d_out;

    char* ws = (char*)d_ws;
    unsigned short* Xb  = (unsigned short*)(ws);
    unsigned short* Wb  = (unsigned short*)(ws + (8u  << 20));
    unsigned short* QKV = (unsigned short*)(ws + (16u << 20));
    unsigned short* Qb  = QKV;
    unsigned short* Kb  = QKV + (size_t)kBS * kD;
    unsigned short* Vb  = QKV + (size_t)2 * kBS * kD;
    unsigned short* Ctx = (unsigned short*)(ws + (40u << 20));
    unsigned short* VT  = (unsigned short*)(ws + (48u << 20));
    float* R            = (float*)(ws + (48u << 20));  // aliases VT

    convert_kernel<<<8192, 256, 0, stream>>>(x, wq, wk, wv, wo, Xb, Wb);

    gemm_nt<0><<<dim3(kD / 128, kBS / 128, 3), 256, 0, stream>>>(
        Xb, Wb, QKV, nullptr, kBS, kD, kD);

    stats_vt_kernel<<<512, 256, 0, stream>>>(Qb, Kb, Vb, VT);

    ctx_kernel<<<512, 256, 0, stream>>>(Qb, Kb, VT, Ctx);

    gemm_nt<1><<<dim3(kD / 128, kBS / 128, 1), 256, 0, stream>>>(
        Ctx, Wb + (size_t)3 * kD * kD, R, x, kBS, kD, kD);

    ln_kernel<<<kBS, 256, 0, stream>>>(R, gamma, beta, out);
}